// Round 1
// baseline (7850.472 us; speedup 1.0000x reference)
//
#include <hip/hip_runtime.h>
#include <math.h>

#define Q 8
#define TPB 256

// ---------- helpers ----------

__device__ __forceinline__ void load8(const float* __restrict__ p, float r[Q]) {
  const float4* p4 = reinterpret_cast<const float4*>(p);
  float4 a = p4[0], b = p4[1];
  r[0]=a.x; r[1]=a.y; r[2]=a.z; r[3]=a.w;
  r[4]=b.x; r[5]=b.y; r[6]=b.z; r[7]=b.w;
}

__device__ __forceinline__ void store8(float* __restrict__ p, const float r[Q]) {
  float4 a, b;
  a.x=r[0]; a.y=r[1]; a.z=r[2]; a.w=r[3];
  b.x=r[4]; b.y=r[5]; b.z=r[6]; b.w=r[7];
  float4* p4 = reinterpret_cast<float4*>(p);
  p4[0]=a; p4[1]=b;
}

__device__ __forceinline__ void softmax8(float x[Q]) {
  float mx = x[0];
#pragma unroll
  for (int j=1;j<Q;j++) mx = fmaxf(mx, x[j]);
  float s = 0.f;
#pragma unroll
  for (int j=0;j<Q;j++) { x[j] = expf(x[j]-mx); s += x[j]; }
  float inv = 1.0f/s;
#pragma unroll
  for (int j=0;j<Q;j++) x[j] *= inv;
}

// wave(64)-reduce a single float; result valid on lane 0 of each wave
__device__ __forceinline__ float wave_sum(float x) {
  x += __shfl_down(x, 32);
  x += __shfl_down(x, 16);
  x += __shfl_down(x, 8);
  x += __shfl_down(x, 4);
  x += __shfl_down(x, 2);
  x += __shfl_down(x, 1);
  return x;
}

// ---------- kernels ----------

// Normalize msg_init rows, compute logterm0, scatter into node_in0.
__global__ void k_init_edges(const float* __restrict__ msg_init,
                             const int* __restrict__ dst,
                             const float* __restrict__ beta,
                             float* __restrict__ lt,
                             float* __restrict__ ni0,
                             int E) {
  int e = blockIdx.x * TPB + threadIdx.x;
  if (e >= E) return;
  float b  = beta[0];
  float ew = expf(b) - 1.0f;
  float r[Q];
  load8(msg_init + (size_t)e * Q, r);
  float s = 0.f;
#pragma unroll
  for (int j=0;j<Q;j++) s += r[j];
  float inv = 1.0f / s;
  float o[Q];
#pragma unroll
  for (int j=0;j<Q;j++) o[j] = log1pf(r[j] * inv * ew);
  store8(lt + (size_t)e * Q, o);
  float* t = ni0 + (size_t)dst[e] * Q;
#pragma unroll
  for (int j=0;j<Q;j++) atomicAdd(t + j, o[j]);
}

// Normalize psi_init rows, accumulate S0[j] = sum_n psi[n][j].
__global__ void k_init_nodes(const float* __restrict__ psi_init,
                             float* __restrict__ S0, int N) {
  int n = blockIdx.x * TPB + threadIdx.x;
  float p[Q];
  if (n < N) {
    load8(psi_init + (size_t)n * Q, p);
    float s = 0.f;
#pragma unroll
    for (int j=0;j<Q;j++) s += p[j];
    float inv = 1.0f / s;
#pragma unroll
    for (int j=0;j<Q;j++) p[j] *= inv;
  } else {
#pragma unroll
    for (int j=0;j<Q;j++) p[j] = 0.f;
  }
#pragma unroll
  for (int j=0;j<Q;j++) {
    float x = wave_sum(p[j]);
    if ((threadIdx.x & 63) == 0) atomicAdd(&S0[j], x);
  }
}

// One iteration's message update: one thread per edge PAIR (i, i+m).
// Reads logterm_t, node_in_t, h_t; writes logterm_{t+1}; accumulates node_in_{t+1}.
__global__ void k_edges(const int* __restrict__ src, const int* __restrict__ dst,
                        const float* __restrict__ beta,
                        const float* __restrict__ ni_cur,
                        float* __restrict__ ni_nxt,
                        float* __restrict__ lt,
                        const float* __restrict__ S,
                        float neg_mw, int m) {
  int i = blockIdx.x * TPB + threadIdx.x;
  if (i >= m) return;
  float b  = beta[0];
  float ew = expf(b) - 1.0f;
  float hb = neg_mw * b;                 // h[j] = -mean_w * b * S[j]
  float h[Q];
#pragma unroll
  for (int j=0;j<Q;j++) h[j] = hb * S[j];

  int u = src[i], v = dst[i];
  float lti[Q], ltr[Q], niu[Q], niv[Q];
  load8(lt + (size_t)i * Q, lti);
  load8(lt + ((size_t)i + (size_t)m) * Q, ltr);
  load8(ni_cur + (size_t)u * Q, niu);
  load8(ni_cur + (size_t)v * Q, niv);

  float a0[Q], a1[Q];
#pragma unroll
  for (int j=0;j<Q;j++) a0[j] = niu[j] - ltr[j] + h[j];  // edge i   (src=u, rev=i+m)
#pragma unroll
  for (int j=0;j<Q;j++) a1[j] = niv[j] - lti[j] + h[j];  // edge i+m (src=v, rev=i)
  softmax8(a0);
  softmax8(a1);
#pragma unroll
  for (int j=0;j<Q;j++) { a0[j] = log1pf(a0[j] * ew); a1[j] = log1pf(a1[j] * ew); }
  store8(lt + (size_t)i * Q, a0);
  store8(lt + ((size_t)i + (size_t)m) * Q, a1);

  float* tv = ni_nxt + (size_t)v * Q;    // dst[i]   = v
  float* tu = ni_nxt + (size_t)u * Q;    // dst[i+m] = u
#pragma unroll
  for (int j=0;j<Q;j++) atomicAdd(tv + j, a0[j]);
#pragma unroll
  for (int j=0;j<Q;j++) atomicAdd(tu + j, a1[j]);
}

// psi_{t+1} = softmax(node_in_t + h_t); accumulate S_{t+1}; store psi on last iter.
__global__ void k_nodes(const float* __restrict__ ni_cur,
                        const float* __restrict__ beta,
                        const float* __restrict__ S,
                        float* __restrict__ S_nxt,
                        float neg_mw,
                        float* __restrict__ psi_out,
                        int N, int storePsi) {
  int n = blockIdx.x * TPB + threadIdx.x;
  float b  = beta[0];
  float hb = neg_mw * b;
  float p[Q];
  if (n < N) {
    load8(ni_cur + (size_t)n * Q, p);
#pragma unroll
    for (int j=0;j<Q;j++) p[j] += hb * S[j];
    softmax8(p);
    if (storePsi) store8(psi_out + (size_t)n * Q, p);
  } else {
#pragma unroll
    for (int j=0;j<Q;j++) p[j] = 0.f;
  }
#pragma unroll
  for (int j=0;j<Q;j++) {
    float x = wave_sum(p[j]);
    if ((threadIdx.x & 63) == 0) atomicAdd(&S_nxt[j], x);
  }
}

// H_acc += sum_n sum_j psi*log(psi+1e-12)
__global__ void k_entropy(const float* __restrict__ psi,
                          float* __restrict__ H_acc, int N) {
  int n = blockIdx.x * TPB + threadIdx.x;
  float s = 0.f;
  if (n < N) {
    float p[Q];
    load8(psi + (size_t)n * Q, p);
#pragma unroll
    for (int j=0;j<Q;j++) s += p[j] * logf(p[j] + 1e-12f);
  }
  float x = wave_sum(s);
  if ((threadIdx.x & 63) == 0) atomicAdd(H_acc, x);
}

// reg_acc += sum (psi[u]-psi[v])^2 ; mod_acc += (argmax equal) * (1-mean_w)
__global__ void k_edge_stats(const float* __restrict__ psi,
                             const int* __restrict__ src,
                             const int* __restrict__ dst,
                             float* __restrict__ reg_acc,
                             float* __restrict__ mod_acc,
                             float one_minus_mw, int m) {
  int i = blockIdx.x * TPB + threadIdx.x;
  float reg = 0.f, mod = 0.f;
  if (i < m) {
    int u = src[i], v = dst[i];
    float pu[Q], pv[Q];
    load8(psi + (size_t)u * Q, pu);
    load8(psi + (size_t)v * Q, pv);
#pragma unroll
    for (int j=0;j<Q;j++) { float d = pu[j] - pv[j]; reg += d * d; }
    int au = 0, av = 0;
    float mu = pu[0], mv = pv[0];
#pragma unroll
    for (int j=1;j<Q;j++) {
      if (pu[j] > mu) { mu = pu[j]; au = j; }
      if (pv[j] > mv) { mv = pv[j]; av = j; }
    }
    if (au == av) mod = one_minus_mw;
  }
  float xr = wave_sum(reg);
  float xm = wave_sum(mod);
  if ((threadIdx.x & 63) == 0) {
    atomicAdd(reg_acc, xr);
    atomicAdd(mod_acc, xm);
  }
}

__global__ void k_finalize(const float* __restrict__ H_acc,
                           const float* __restrict__ reg_acc,
                           const float* __restrict__ mod_acc,
                           float* __restrict__ out3,
                           float inv_m, float inv_N, float entc) {
  out3[0] = reg_acc[0] * inv_m;
  out3[1] = (-H_acc[0] * inv_N) * entc;
  out3[2] = mod_acc[0] * inv_m;
}

// ---------- host ----------

extern "C" void kernel_launch(void* const* d_in, const int* in_sizes, int n_in,
                              void* d_out, int out_size, void* d_ws, size_t ws_size,
                              hipStream_t stream) {
  const float* msg_init = (const float*)d_in[0];
  const float* psi_init = (const float*)d_in[1];
  const float* beta     = (const float*)d_in[2];
  const int*   src      = (const int*)d_in[3];
  const int*   dst      = (const int*)d_in[4];

  const int E = in_sizes[3];
  const int m = E / 2;
  const int N = in_sizes[1] / Q;
  const double mean_w = (double)E / ((double)N * (double)N);
  const float  neg_mw = (float)(-mean_w);

  float* out = (float*)d_out;

  // workspace layout
  float* lt  = (float*)d_ws;                 // E*Q
  float* ni0 = lt  + (size_t)E * Q;          // N*Q
  float* ni1 = ni0 + (size_t)N * Q;          // N*Q
  float* S   = ni1 + (size_t)N * Q;          // 11*Q (S_0..S_10)
  float* H_acc   = S + 11 * Q;
  float* reg_acc = H_acc + 1;
  float* mod_acc = H_acc + 2;

  hipMemsetAsync(ni0, 0, (size_t)N * Q * sizeof(float), stream);
  hipMemsetAsync(S,   0, (size_t)(11 * Q + 3) * sizeof(float), stream);

  const int gridE = (E + TPB - 1) / TPB;
  const int gridM = (m + TPB - 1) / TPB;
  const int gridN = (N + TPB - 1) / TPB;

  k_init_edges<<<gridE, TPB, 0, stream>>>(msg_init, dst, beta, lt, ni0, E);
  k_init_nodes<<<gridN, TPB, 0, stream>>>(psi_init, S, N);

  float* bufs[2] = { ni0, ni1 };
  for (int t = 0; t < 10; ++t) {
    float* cur = bufs[t & 1];
    float* nxt = bufs[(t + 1) & 1];
    if (t < 9) {
      hipMemsetAsync(nxt, 0, (size_t)N * Q * sizeof(float), stream);
      k_edges<<<gridM, TPB, 0, stream>>>(src, dst, beta, cur, nxt, lt,
                                         S + t * Q, neg_mw, m);
    }
    k_nodes<<<gridN, TPB, 0, stream>>>(cur, beta, S + t * Q, S + (t + 1) * Q,
                                       neg_mw, out, N, (t == 9) ? 1 : 0);
  }

  k_entropy<<<gridN, TPB, 0, stream>>>(out, H_acc, N);
  k_edge_stats<<<gridM, TPB, 0, stream>>>(out, src, dst, reg_acc, mod_acc,
                                          (float)(1.0 - mean_w), m);
  const float entc = (float)(4.0 * log(0.5) / log(1.0 / (double)Q));
  k_finalize<<<1, 1, 0, stream>>>(H_acc, reg_acc, mod_acc, out + (size_t)N * Q,
                                  (float)(1.0 / (double)m), (float)(1.0 / (double)N),
                                  entc);
}

// Round 2
// 1964.639 us; speedup vs baseline: 3.9959x; 3.9959x over previous
//
#include <hip/hip_runtime.h>
#include <math.h>

#define Q 8
#define TPB 256

// ---------- helpers ----------

__device__ __forceinline__ void load8(const float* __restrict__ p, float r[Q]) {
  const float4* p4 = reinterpret_cast<const float4*>(p);
  float4 a = p4[0], b = p4[1];
  r[0]=a.x; r[1]=a.y; r[2]=a.z; r[3]=a.w;
  r[4]=b.x; r[5]=b.y; r[6]=b.z; r[7]=b.w;
}

__device__ __forceinline__ void store8(float* __restrict__ p, const float r[Q]) {
  float4 a, b;
  a.x=r[0]; a.y=r[1]; a.z=r[2]; a.w=r[3];
  b.x=r[4]; b.y=r[5]; b.z=r[6]; b.w=r[7];
  float4* p4 = reinterpret_cast<float4*>(p);
  p4[0]=a; p4[1]=b;
}

__device__ __forceinline__ void softmax8(float x[Q]) {
  float mx = x[0];
#pragma unroll
  for (int j=1;j<Q;j++) mx = fmaxf(mx, x[j]);
  float s = 0.f;
#pragma unroll
  for (int j=0;j<Q;j++) { x[j] = expf(x[j]-mx); s += x[j]; }
  float inv = 1.0f/s;
#pragma unroll
  for (int j=0;j<Q;j++) x[j] *= inv;
}

__device__ __forceinline__ float wave_sum(float x) {
  x += __shfl_down(x, 32);
  x += __shfl_down(x, 16);
  x += __shfl_down(x, 8);
  x += __shfl_down(x, 4);
  x += __shfl_down(x, 2);
  x += __shfl_down(x, 1);
  return x;
}

// ---------- CSR build (once) ----------

__global__ void k_count(const int* __restrict__ dst, int* __restrict__ cnt, int E) {
  int e = blockIdx.x * TPB + threadIdx.x;
  if (e < E) atomicAdd(&cnt[dst[e]], 1);
}

// single block, 1024 threads: exclusive scan of cnt (in cursor buf) -> row_ptr, cursor
__global__ void k_scan(int* __restrict__ cnt_cursor, int* __restrict__ row_ptr, int N) {
  __shared__ int part[1024];
  const int tid = threadIdx.x;
  const int chunk = (N + 1023) / 1024;
  const int s = tid * chunk;
  const int e = min(s + chunk, N);
  int sum = 0;
  for (int i = s; i < e; i++) sum += cnt_cursor[i];
  part[tid] = sum;
  __syncthreads();
  // inclusive scan (Hillis-Steele with explicit double sync)
  for (int off = 1; off < 1024; off <<= 1) {
    int v = (tid >= off) ? part[tid - off] : 0;
    __syncthreads();
    part[tid] += v;
    __syncthreads();
  }
  int run = (tid > 0) ? part[tid - 1] : 0;
  for (int i = s; i < e; i++) {
    int c = cnt_cursor[i];
    row_ptr[i] = run;
    cnt_cursor[i] = run;   // becomes cursor
    run += c;
  }
  if (tid == 1023) row_ptr[N] = part[1023];
}

__global__ void k_fill(const int* __restrict__ dst, int* __restrict__ cursor,
                       int* __restrict__ eid, int E) {
  int e = blockIdx.x * TPB + threadIdx.x;
  if (e < E) {
    int p = atomicAdd(&cursor[dst[e]], 1);
    eid[p] = e;
  }
}

// ---------- init ----------

// Normalize msg_init rows -> logterm0 (no scatter).
__global__ void k_init_edges(const float* __restrict__ msg_init,
                             const float* __restrict__ beta,
                             float* __restrict__ lt, int E) {
  int e = blockIdx.x * TPB + threadIdx.x;
  if (e >= E) return;
  float b  = beta[0];
  float ew = expf(b) - 1.0f;
  float r[Q];
  load8(msg_init + (size_t)e * Q, r);
  float s = 0.f;
#pragma unroll
  for (int j=0;j<Q;j++) s += r[j];
  float inv = 1.0f / s;
#pragma unroll
  for (int j=0;j<Q;j++) r[j] = log1pf(r[j] * inv * ew);
  store8(lt + (size_t)e * Q, r);
}

// Normalize psi_init rows, accumulate S0[j].
__global__ void k_init_nodes(const float* __restrict__ psi_init,
                             float* __restrict__ S0, int N) {
  int n = blockIdx.x * TPB + threadIdx.x;
  float p[Q];
  if (n < N) {
    load8(psi_init + (size_t)n * Q, p);
    float s = 0.f;
#pragma unroll
    for (int j=0;j<Q;j++) s += p[j];
    float inv = 1.0f / s;
#pragma unroll
    for (int j=0;j<Q;j++) p[j] *= inv;
  } else {
#pragma unroll
    for (int j=0;j<Q;j++) p[j] = 0.f;
  }
#pragma unroll
  for (int j=0;j<Q;j++) {
    float x = wave_sum(p[j]);
    if ((threadIdx.x & 63) == 0) atomicAdd(&S0[j], x);
  }
}

// ---------- per-iteration ----------

// Gather segment-sum via CSR (8 lanes per node) + fused psi softmax + S reduce.
// ni[n][j] = sum_{e: dst[e]=n} lt[e][j];  psi = softmax(ni + h);  S_nxt += psi
__global__ void k_gather_nodes(const int* __restrict__ row_ptr,
                               const int* __restrict__ eid,
                               const float* __restrict__ lt,
                               const float* __restrict__ beta,
                               const float* __restrict__ S,
                               float* __restrict__ S_nxt,
                               float* __restrict__ ni,
                               float* __restrict__ psi_out,
                               float neg_mw, int N, int storePsi) {
  __shared__ float part[4][Q];
  const int tid = threadIdx.x;
  const int g = tid >> 3;       // group 0..31
  const int j = tid & 7;        // component
  const int n = blockIdx.x * 32 + g;
  const float hb = neg_mw * beta[0];

  float p = 0.f;
  if (n < N) {
    const int s = row_ptr[n], e = row_ptr[n + 1];
    float acc = 0.f;
    for (int k = s; k < e; k++) {
      acc += lt[(size_t)eid[k] * Q + j];
    }
    ni[(size_t)n * Q + j] = acc;
    float x = acc + hb * S[j];
    // softmax across the 8 lanes of this group
    float mx = x;
    mx = fmaxf(mx, __shfl_xor(mx, 1));
    mx = fmaxf(mx, __shfl_xor(mx, 2));
    mx = fmaxf(mx, __shfl_xor(mx, 4));
    float ex = expf(x - mx);
    float sm = ex;
    sm += __shfl_xor(sm, 1);
    sm += __shfl_xor(sm, 2);
    sm += __shfl_xor(sm, 4);
    p = ex / sm;
    if (storePsi) psi_out[(size_t)n * Q + j] = p;
  }
  // reduce psi over groups: lane l accumulates component l&7
  float t = p;
  t += __shfl_xor(t, 8);
  t += __shfl_xor(t, 16);
  t += __shfl_xor(t, 32);
  if ((tid & 63) < 8) part[tid >> 6][j] = t;
  __syncthreads();
  if (tid < Q) {
    float tot = part[0][tid] + part[1][tid] + part[2][tid] + part[3][tid];
    atomicAdd(&S_nxt[tid], tot);
  }
}

// Message update, one thread per edge PAIR (i, i+m). In-place lt update, no atomics.
__global__ void k_edges(const int* __restrict__ src, const int* __restrict__ dst,
                        const float* __restrict__ beta,
                        const float* __restrict__ ni,
                        float* __restrict__ lt,
                        const float* __restrict__ S,
                        float neg_mw, int m) {
  int i = blockIdx.x * TPB + threadIdx.x;
  if (i >= m) return;
  float b  = beta[0];
  float ew = expf(b) - 1.0f;
  float hb = neg_mw * b;
  float h[Q];
#pragma unroll
  for (int j=0;j<Q;j++) h[j] = hb * S[j];

  int u = src[i], v = dst[i];
  float lti[Q], ltr[Q], niu[Q], niv[Q];
  load8(lt + (size_t)i * Q, lti);
  load8(lt + ((size_t)i + (size_t)m) * Q, ltr);
  load8(ni + (size_t)u * Q, niu);
  load8(ni + (size_t)v * Q, niv);

  float a0[Q], a1[Q];
#pragma unroll
  for (int j=0;j<Q;j++) a0[j] = niu[j] - ltr[j] + h[j];  // edge i   (src=u, rev=i+m)
#pragma unroll
  for (int j=0;j<Q;j++) a1[j] = niv[j] - lti[j] + h[j];  // edge i+m (src=v, rev=i)
  softmax8(a0);
  softmax8(a1);
#pragma unroll
  for (int j=0;j<Q;j++) { a0[j] = log1pf(a0[j] * ew); a1[j] = log1pf(a1[j] * ew); }
  store8(lt + (size_t)i * Q, a0);
  store8(lt + ((size_t)i + (size_t)m) * Q, a1);
}

// ---------- stats ----------

__global__ void k_entropy(const float* __restrict__ psi,
                          float* __restrict__ H_acc, int N) {
  int n = blockIdx.x * TPB + threadIdx.x;
  float s = 0.f;
  if (n < N) {
    float p[Q];
    load8(psi + (size_t)n * Q, p);
#pragma unroll
    for (int j=0;j<Q;j++) s += p[j] * logf(p[j] + 1e-12f);
  }
  float x = wave_sum(s);
  if ((threadIdx.x & 63) == 0) atomicAdd(H_acc, x);
}

__global__ void k_edge_stats(const float* __restrict__ psi,
                             const int* __restrict__ src,
                             const int* __restrict__ dst,
                             float* __restrict__ reg_acc,
                             float* __restrict__ mod_acc,
                             float one_minus_mw, int m) {
  int i = blockIdx.x * TPB + threadIdx.x;
  float reg = 0.f, mod = 0.f;
  if (i < m) {
    int u = src[i], v = dst[i];
    float pu[Q], pv[Q];
    load8(psi + (size_t)u * Q, pu);
    load8(psi + (size_t)v * Q, pv);
#pragma unroll
    for (int j=0;j<Q;j++) { float d = pu[j] - pv[j]; reg += d * d; }
    int au = 0, av = 0;
    float mu = pu[0], mv = pv[0];
#pragma unroll
    for (int j=1;j<Q;j++) {
      if (pu[j] > mu) { mu = pu[j]; au = j; }
      if (pv[j] > mv) { mv = pv[j]; av = j; }
    }
    if (au == av) mod = one_minus_mw;
  }
  float xr = wave_sum(reg);
  float xm = wave_sum(mod);
  if ((threadIdx.x & 63) == 0) {
    atomicAdd(reg_acc, xr);
    atomicAdd(mod_acc, xm);
  }
}

__global__ void k_finalize(const float* __restrict__ H_acc,
                           const float* __restrict__ reg_acc,
                           const float* __restrict__ mod_acc,
                           float* __restrict__ out3,
                           float inv_m, float inv_N, float entc) {
  out3[0] = reg_acc[0] * inv_m;
  out3[1] = (-H_acc[0] * inv_N) * entc;
  out3[2] = mod_acc[0] * inv_m;
}

// ---------- host ----------

extern "C" void kernel_launch(void* const* d_in, const int* in_sizes, int n_in,
                              void* d_out, int out_size, void* d_ws, size_t ws_size,
                              hipStream_t stream) {
  const float* msg_init = (const float*)d_in[0];
  const float* psi_init = (const float*)d_in[1];
  const float* beta     = (const float*)d_in[2];
  const int*   src      = (const int*)d_in[3];
  const int*   dst      = (const int*)d_in[4];

  const int E = in_sizes[3];
  const int m = E / 2;
  const int N = in_sizes[1] / Q;
  const double mean_w = (double)E / ((double)N * (double)N);
  const float  neg_mw = (float)(-mean_w);

  float* out = (float*)d_out;

  // workspace layout
  float* lt   = (float*)d_ws;                    // E*Q floats
  float* ni   = lt + (size_t)E * Q;              // N*Q
  float* S    = ni + (size_t)N * Q;              // 11*Q
  float* H_acc   = S + 11 * Q;                   // 1
  float* reg_acc = H_acc + 1;                    // 1
  float* mod_acc = H_acc + 2;                    // 1
  int*   row_ptr = (int*)(H_acc + 3);            // N+1
  int*   cursor  = row_ptr + (N + 1);            // N (counts, then cursors)
  int*   eid     = cursor + N;                   // E

  hipMemsetAsync(S, 0, (size_t)(11 * Q + 3) * sizeof(float), stream);
  hipMemsetAsync(cursor, 0, (size_t)N * sizeof(int), stream);

  const int gridE = (E + TPB - 1) / TPB;
  const int gridM = (m + TPB - 1) / TPB;
  const int gridN = (N + TPB - 1) / TPB;
  const int gridG = (N + 31) / 32;

  // CSR build (dst is iteration-invariant)
  k_count<<<gridE, TPB, 0, stream>>>(dst, cursor, E);
  k_scan<<<1, 1024, 0, stream>>>(cursor, row_ptr, N);
  k_fill<<<gridE, TPB, 0, stream>>>(dst, cursor, eid, E);

  // init
  k_init_edges<<<gridE, TPB, 0, stream>>>(msg_init, beta, lt, E);
  k_init_nodes<<<gridN, TPB, 0, stream>>>(psi_init, S, N);

  // iterations: G_t (ni_t = segsum(lt_t), psi_{t+1}, S_{t+1}) ; E_t (lt_{t+1})
  for (int t = 0; t < 10; ++t) {
    k_gather_nodes<<<gridG, TPB, 0, stream>>>(row_ptr, eid, lt, beta,
                                              S + t * Q, S + (t + 1) * Q,
                                              ni, out, neg_mw, N, (t == 9) ? 1 : 0);
    if (t < 9) {
      k_edges<<<gridM, TPB, 0, stream>>>(src, dst, beta, ni, lt,
                                         S + t * Q, neg_mw, m);
    }
  }

  k_entropy<<<gridN, TPB, 0, stream>>>(out, H_acc, N);
  k_edge_stats<<<gridM, TPB, 0, stream>>>(out, src, dst, reg_acc, mod_acc,
                                          (float)(1.0 - mean_w), m);
  const float entc = (float)(4.0 * log(0.5) / log(1.0 / (double)Q));
  k_finalize<<<1, 1, 0, stream>>>(H_acc, reg_acc, mod_acc, out + (size_t)N * Q,
                                  (float)(1.0 / (double)m), (float)(1.0 / (double)N),
                                  entc);
}

// Round 3
// 1164.793 us; speedup vs baseline: 6.7398x; 1.6867x over previous
//
#include <hip/hip_runtime.h>
#include <math.h>

#define Q 8
#define TPB 256
#define WPB (TPB / 64)   // waves per block

// ---------- helpers ----------

__device__ __forceinline__ void load8(const float* __restrict__ p, float r[Q]) {
  const float4* p4 = reinterpret_cast<const float4*>(p);
  float4 a = p4[0], b = p4[1];
  r[0]=a.x; r[1]=a.y; r[2]=a.z; r[3]=a.w;
  r[4]=b.x; r[5]=b.y; r[6]=b.z; r[7]=b.w;
}

__device__ __forceinline__ void store8(float* __restrict__ p, const float r[Q]) {
  float4 a, b;
  a.x=r[0]; a.y=r[1]; a.z=r[2]; a.w=r[3];
  b.x=r[4]; b.y=r[5]; b.z=r[6]; b.w=r[7];
  float4* p4 = reinterpret_cast<float4*>(p);
  p4[0]=a; p4[1]=b;
}

__device__ __forceinline__ void softmax8(float x[Q]) {
  float mx = x[0];
#pragma unroll
  for (int j=1;j<Q;j++) mx = fmaxf(mx, x[j]);
  float s = 0.f;
#pragma unroll
  for (int j=0;j<Q;j++) { x[j] = expf(x[j]-mx); s += x[j]; }
  float inv = 1.0f/s;
#pragma unroll
  for (int j=0;j<Q;j++) x[j] *= inv;
}

// softmax across the 8 lanes of a slot (lane = slot*8 + j); returns this lane's prob
__device__ __forceinline__ float softmax8_lanes(float x) {
  float mx = x;
  mx = fmaxf(mx, __shfl_xor(mx, 1));
  mx = fmaxf(mx, __shfl_xor(mx, 2));
  mx = fmaxf(mx, __shfl_xor(mx, 4));
  float ex = expf(x - mx);
  float s = ex;
  s += __shfl_xor(s, 1);
  s += __shfl_xor(s, 2);
  s += __shfl_xor(s, 4);
  return ex / s;
}

__device__ __forceinline__ float wave_sum(float x) {
  x += __shfl_down(x, 32);
  x += __shfl_down(x, 16);
  x += __shfl_down(x, 8);
  x += __shfl_down(x, 4);
  x += __shfl_down(x, 2);
  x += __shfl_down(x, 1);
  return x;
}

// block-wide sum of x -> single atomicAdd(target). lds must hold WPB floats.
__device__ __forceinline__ void block_reduce_atomic(float x, float* target, float* lds) {
  float w = wave_sum(x);
  const int lane = threadIdx.x & 63, wid = threadIdx.x >> 6;
  if (lane == 0) lds[wid] = w;
  __syncthreads();
  if (threadIdx.x == 0) {
    float t = 0.f;
#pragma unroll
    for (int i = 0; i < WPB; i++) t += lds[i];
    atomicAdd(target, t);
  }
  __syncthreads();
}

// ---------- CSR build (once per call) ----------

__global__ void k_count(const int* __restrict__ dst, int* __restrict__ cnt, int E) {
  int e = blockIdx.x * TPB + threadIdx.x;
  if (e < E) atomicAdd(&cnt[dst[e]], 1);
}

__global__ void k_scan(int* __restrict__ cnt_cursor, int* __restrict__ row_ptr, int N) {
  __shared__ int part[1024];
  const int tid = threadIdx.x;
  const int chunk = (N + 1023) / 1024;
  const int s = tid * chunk;
  const int e = min(s + chunk, N);
  int sum = 0;
  for (int i = s; i < e; i++) sum += cnt_cursor[i];
  part[tid] = sum;
  __syncthreads();
  for (int off = 1; off < 1024; off <<= 1) {
    int v = (tid >= off) ? part[tid - off] : 0;
    __syncthreads();
    part[tid] += v;
    __syncthreads();
  }
  int run = (tid > 0) ? part[tid - 1] : 0;
  for (int i = s; i < e; i++) {
    int c = cnt_cursor[i];
    row_ptr[i] = run;
    cnt_cursor[i] = run;
    run += c;
  }
  if (tid == 1023) row_ptr[N] = part[1023];
}

__global__ void k_fill_pos(const int* __restrict__ dst, int* __restrict__ cursor,
                           int* __restrict__ pos, int E) {
  int e = blockIdx.x * TPB + threadIdx.x;
  if (e < E) { int p = atomicAdd(&cursor[dst[e]], 1); pos[e] = p; }
}

__global__ void k_fill_eid(const int* __restrict__ dst, int* __restrict__ cursor,
                           int* __restrict__ eid, int E) {
  int e = blockIdx.x * TPB + threadIdx.x;
  if (e < E) { int p = atomicAdd(&cursor[dst[e]], 1); eid[p] = e; }
}

__global__ void k_revp(const int* __restrict__ pos, int* __restrict__ revp, int m) {
  int i = blockIdx.x * TPB + threadIdx.x;
  if (i < m) {
    int p  = pos[i];
    int pr = pos[i + m];
    revp[p]  = pr;
    revp[pr] = p;
  }
}

// ---------- init ----------

// Path A: normalize msg rows -> logterm0, scattered into CSR position.
__global__ void k_init_edges_pos(const float* __restrict__ msg_init,
                                 const int* __restrict__ pos,
                                 const float* __restrict__ beta,
                                 float* __restrict__ ltA, int E) {
  int e = blockIdx.x * TPB + threadIdx.x;
  if (e >= E) return;
  float b  = beta[0];
  float ew = expf(b) - 1.0f;
  float r[Q];
  load8(msg_init + (size_t)e * Q, r);
  float s = 0.f;
#pragma unroll
  for (int j=0;j<Q;j++) s += r[j];
  float inv = 1.0f / s;
#pragma unroll
  for (int j=0;j<Q;j++) r[j] = log1pf(r[j] * inv * ew);
  store8(ltA + (size_t)pos[e] * Q, r);
}

// Path B: normalize msg rows -> logterm0 in edge order.
__global__ void k_init_edges(const float* __restrict__ msg_init,
                             const float* __restrict__ beta,
                             float* __restrict__ lt, int E) {
  int e = blockIdx.x * TPB + threadIdx.x;
  if (e >= E) return;
  float b  = beta[0];
  float ew = expf(b) - 1.0f;
  float r[Q];
  load8(msg_init + (size_t)e * Q, r);
  float s = 0.f;
#pragma unroll
  for (int j=0;j<Q;j++) s += r[j];
  float inv = 1.0f / s;
#pragma unroll
  for (int j=0;j<Q;j++) r[j] = log1pf(r[j] * inv * ew);
  store8(lt + (size_t)e * Q, r);
}

__global__ void k_init_nodes(const float* __restrict__ psi_init,
                             float* __restrict__ S0, int N) {
  __shared__ float lds[WPB];
  int n = blockIdx.x * TPB + threadIdx.x;
  float p[Q];
  if (n < N) {
    load8(psi_init + (size_t)n * Q, p);
    float s = 0.f;
#pragma unroll
    for (int j=0;j<Q;j++) s += p[j];
    float inv = 1.0f / s;
#pragma unroll
    for (int j=0;j<Q;j++) p[j] *= inv;
  } else {
#pragma unroll
    for (int j=0;j<Q;j++) p[j] = 0.f;
  }
#pragma unroll
  for (int j=0;j<Q;j++) {
    block_reduce_atomic(p[j], &S0[j], lds);
  }
}

// ---------- Path A: fused per-node iteration ----------
// One wave per node (grid-stride). lane = slot*8 + j ; slot handles rows s+slot, s+slot+8, ...
// Streams the node's contiguous CSR rows of ltA (coalesced), reduces to ni in
// registers, computes psi -> S_nxt, and writes all rev-messages into ltB
// (scattered 32B stores). No ni buffer, no scattered reads.
__global__ void k_fused(const int* __restrict__ row_ptr,
                        const int* __restrict__ revp,
                        const float* __restrict__ ltA,
                        float* __restrict__ ltB,
                        const float* __restrict__ beta,
                        const float* __restrict__ S,
                        float* __restrict__ S_nxt,
                        float neg_mw, int N) {
  __shared__ float part[WPB][Q];
  const int lane = threadIdx.x & 63;
  const int wid  = threadIdx.x >> 6;
  const int slot = lane >> 3;
  const int j    = lane & 7;
  const float b  = beta[0];
  const float ew = expf(b) - 1.0f;
  const float h  = neg_mw * b * S[j];
  float sacc = 0.f;

  const int wg = blockIdx.x * WPB + wid;
  const int ws = gridDim.x * WPB;
  for (int u = wg; u < N; u += ws) {
    const int s = row_ptr[u], e = row_ptr[u + 1];
    float acc = 0.f;
    for (int r = s + slot; r < e; r += 8) acc += ltA[(size_t)r * Q + j];
    acc += __shfl_xor(acc, 8);
    acc += __shfl_xor(acc, 16);
    acc += __shfl_xor(acc, 32);
    const float x = acc + h;                 // ni[u][j] + h[j], same on all slots
    float p = softmax8_lanes(x);             // psi_{t+1}[u][j]
    if (slot == 0) sacc += p;
    for (int r = s + slot; r < e; r += 8) {
      float v = ltA[(size_t)r * Q + j];      // L1-hot reload
      float pm = softmax8_lanes(x - v);      // new msg on edge rev(r)
      float o = log1pf(pm * ew);
      ltB[(size_t)revp[r] * Q + j] = o;      // 32B scattered store per slot
    }
  }
  if (slot == 0) part[wid][j] = sacc;
  __syncthreads();
  if (threadIdx.x < Q) {
    float tot = 0.f;
#pragma unroll
    for (int w = 0; w < WPB; w++) tot += part[w][threadIdx.x];
    atomicAdd(&S_nxt[threadIdx.x], tot);
  }
}

// Final psi: psi = softmax(segsum(lt) + h), store to out.
__global__ void k_psi_out(const int* __restrict__ row_ptr,
                          const float* __restrict__ ltA,
                          const float* __restrict__ beta,
                          const float* __restrict__ S,
                          float neg_mw, float* __restrict__ psi, int N) {
  const int lane = threadIdx.x & 63;
  const int wid  = threadIdx.x >> 6;
  const int slot = lane >> 3;
  const int j    = lane & 7;
  const float h  = neg_mw * beta[0] * S[j];
  const int wg = blockIdx.x * WPB + wid;
  const int ws = gridDim.x * WPB;
  for (int u = wg; u < N; u += ws) {
    const int s = row_ptr[u], e = row_ptr[u + 1];
    float acc = 0.f;
    for (int r = s + slot; r < e; r += 8) acc += ltA[(size_t)r * Q + j];
    acc += __shfl_xor(acc, 8);
    acc += __shfl_xor(acc, 16);
    acc += __shfl_xor(acc, 32);
    float p = softmax8_lanes(acc + h);
    if (slot == 0) psi[(size_t)u * Q + j] = p;
  }
}

// ---------- Path B (fallback): gather + edges, improved ----------

__global__ void k_gatherB(const int* __restrict__ row_ptr,
                          const int* __restrict__ eid,
                          const float* __restrict__ lt,
                          const float* __restrict__ beta,
                          const float* __restrict__ S,
                          float* __restrict__ S_nxt,
                          float* __restrict__ ni,
                          float* __restrict__ psi_out,
                          float neg_mw, int N, int storePsi) {
  __shared__ float part[WPB][Q];
  const int lane = threadIdx.x & 63;
  const int wid  = threadIdx.x >> 6;
  const int slot = lane >> 3;
  const int j    = lane & 7;
  const float h  = neg_mw * beta[0] * S[j];
  float sacc = 0.f;
  const int wg = blockIdx.x * WPB + wid;
  const int ws = gridDim.x * WPB;
  for (int u = wg; u < N; u += ws) {
    const int s = row_ptr[u], e = row_ptr[u + 1];
    float acc = 0.f;
    for (int r = s + slot; r < e; r += 8) acc += lt[(size_t)eid[r] * Q + j];
    acc += __shfl_xor(acc, 8);
    acc += __shfl_xor(acc, 16);
    acc += __shfl_xor(acc, 32);
    if (slot == 0) ni[(size_t)u * Q + j] = acc;
    float p = softmax8_lanes(acc + h);
    if (slot == 0) {
      sacc += p;
      if (storePsi) psi_out[(size_t)u * Q + j] = p;
    }
  }
  if (slot == 0) part[wid][j] = sacc;
  __syncthreads();
  if (threadIdx.x < Q) {
    float tot = 0.f;
#pragma unroll
    for (int w = 0; w < WPB; w++) tot += part[w][threadIdx.x];
    atomicAdd(&S_nxt[threadIdx.x], tot);
  }
}

__global__ void k_edges(const int* __restrict__ src, const int* __restrict__ dst,
                        const float* __restrict__ beta,
                        const float* __restrict__ ni,
                        float* __restrict__ lt,
                        const float* __restrict__ S,
                        float neg_mw, int m) {
  int i = blockIdx.x * TPB + threadIdx.x;
  if (i >= m) return;
  float b  = beta[0];
  float ew = expf(b) - 1.0f;
  float hb = neg_mw * b;
  float h[Q];
#pragma unroll
  for (int j=0;j<Q;j++) h[j] = hb * S[j];

  int u = src[i], v = dst[i];
  float lti[Q], ltr[Q], niu[Q], niv[Q];
  load8(lt + (size_t)i * Q, lti);
  load8(lt + ((size_t)i + (size_t)m) * Q, ltr);
  load8(ni + (size_t)u * Q, niu);
  load8(ni + (size_t)v * Q, niv);

  float a0[Q], a1[Q];
#pragma unroll
  for (int j=0;j<Q;j++) a0[j] = niu[j] - ltr[j] + h[j];
#pragma unroll
  for (int j=0;j<Q;j++) a1[j] = niv[j] - lti[j] + h[j];
  softmax8(a0);
  softmax8(a1);
#pragma unroll
  for (int j=0;j<Q;j++) { a0[j] = log1pf(a0[j] * ew); a1[j] = log1pf(a1[j] * ew); }
  store8(lt + (size_t)i * Q, a0);
  store8(lt + ((size_t)i + (size_t)m) * Q, a1);
}

// ---------- stats ----------

__global__ void k_entropy(const float* __restrict__ psi,
                          float* __restrict__ H_acc, int N) {
  __shared__ float lds[WPB];
  float s = 0.f;
  for (int n = blockIdx.x * TPB + threadIdx.x; n < N; n += gridDim.x * TPB) {
    float p[Q];
    load8(psi + (size_t)n * Q, p);
#pragma unroll
    for (int j=0;j<Q;j++) s += p[j] * logf(p[j] + 1e-12f);
  }
  block_reduce_atomic(s, H_acc, lds);
}

__global__ void k_edge_stats(const float* __restrict__ psi,
                             const int* __restrict__ src,
                             const int* __restrict__ dst,
                             float* __restrict__ reg_acc,
                             float* __restrict__ mod_acc,
                             float one_minus_mw, int m) {
  __shared__ float lds1[WPB];
  __shared__ float lds2[WPB];
  float reg = 0.f, mod = 0.f;
  for (int i = blockIdx.x * TPB + threadIdx.x; i < m; i += gridDim.x * TPB) {
    int u = src[i], v = dst[i];
    float pu[Q], pv[Q];
    load8(psi + (size_t)u * Q, pu);
    load8(psi + (size_t)v * Q, pv);
#pragma unroll
    for (int j=0;j<Q;j++) { float d = pu[j] - pv[j]; reg += d * d; }
    int au = 0, av = 0;
    float mu = pu[0], mv = pv[0];
#pragma unroll
    for (int j=1;j<Q;j++) {
      if (pu[j] > mu) { mu = pu[j]; au = j; }
      if (pv[j] > mv) { mv = pv[j]; av = j; }
    }
    if (au == av) mod += one_minus_mw;
  }
  block_reduce_atomic(reg, reg_acc, lds1);
  block_reduce_atomic(mod, mod_acc, lds2);
}

__global__ void k_finalize(const float* __restrict__ H_acc,
                           const float* __restrict__ reg_acc,
                           const float* __restrict__ mod_acc,
                           float* __restrict__ out3,
                           float inv_m, float inv_N, float entc) {
  out3[0] = reg_acc[0] * inv_m;
  out3[1] = (-H_acc[0] * inv_N) * entc;
  out3[2] = mod_acc[0] * inv_m;
}

// ---------- host ----------

extern "C" void kernel_launch(void* const* d_in, const int* in_sizes, int n_in,
                              void* d_out, int out_size, void* d_ws, size_t ws_size,
                              hipStream_t stream) {
  const float* msg_init = (const float*)d_in[0];
  const float* psi_init = (const float*)d_in[1];
  const float* beta     = (const float*)d_in[2];
  const int*   src      = (const int*)d_in[3];
  const int*   dst      = (const int*)d_in[4];

  const int E = in_sizes[3];
  const int m = E / 2;
  const int N = in_sizes[1] / Q;
  const double mean_w = (double)E / ((double)N * (double)N);
  const float  neg_mw = (float)(-mean_w);

  float* out = (float*)d_out;

  const int gridE = (E + TPB - 1) / TPB;
  const int gridM = (m + TPB - 1) / TPB;
  const int gridN = (N + TPB - 1) / TPB;
  const int gridF = min(1024, (N + WPB - 1) / WPB);   // fused / gather waves
  const int gridS = min(512, gridM);                  // edge stats

  const float entc  = (float)(4.0 * log(0.5) / log(1.0 / (double)Q));
  const float inv_m = (float)(1.0 / (double)m);
  const float inv_N = (float)(1.0 / (double)N);
  const float omw   = (float)(1.0 - mean_w);

  // Path A footprint: ltA + ltB + revp + row_ptr + cursor + S/accs
  size_t needA = (size_t)2 * E * Q * sizeof(float) + (size_t)E * sizeof(int)
               + (size_t)(N + 1) * sizeof(int) + (size_t)N * sizeof(int)
               + (size_t)(11 * Q + 3) * sizeof(float) + 1024;

  if (ws_size >= needA) {
    // ---------------- Path A: fused, double-buffered, CSR-ordered lt ----------------
    float* ltA = (float*)d_ws;                          // E*Q
    float* ltB = ltA + (size_t)E * Q;                   // E*Q
    int* revp    = (int*)(ltB + (size_t)E * Q);         // E
    int* row_ptr = revp + E;                            // N+1
    int* cursor  = row_ptr + (N + 1);                   // N
    float* S     = (float*)(cursor + N);                // 11*Q
    float* H_acc   = S + 11 * Q;
    float* reg_acc = H_acc + 1;
    float* mod_acc = H_acc + 2;
    int* pos = (int*)ltB;   // alias: pos only live before first fused iteration

    hipMemsetAsync(cursor, 0, (size_t)N * sizeof(int), stream);
    hipMemsetAsync(S, 0, (size_t)(11 * Q + 3) * sizeof(float), stream);

    k_count<<<gridE, TPB, 0, stream>>>(dst, cursor, E);
    k_scan<<<1, 1024, 0, stream>>>(cursor, row_ptr, N);
    k_fill_pos<<<gridE, TPB, 0, stream>>>(dst, cursor, pos, E);
    k_revp<<<gridM, TPB, 0, stream>>>(pos, revp, m);
    k_init_edges_pos<<<gridE, TPB, 0, stream>>>(msg_init, pos, beta, ltA, E);
    k_init_nodes<<<gridN, TPB, 0, stream>>>(psi_init, S, N);

    float* cur = ltA;
    float* nxt = ltB;
    for (int t = 0; t < 9; ++t) {
      k_fused<<<gridF, TPB, 0, stream>>>(row_ptr, revp, cur, nxt, beta,
                                         S + t * Q, S + (t + 1) * Q, neg_mw, N);
      float* tmp = cur; cur = nxt; nxt = tmp;
    }
    k_psi_out<<<gridF, TPB, 0, stream>>>(row_ptr, cur, beta, S + 9 * Q,
                                         neg_mw, out, N);

    k_entropy<<<gridN, TPB, 0, stream>>>(out, H_acc, N);
    k_edge_stats<<<gridS, TPB, 0, stream>>>(out, src, dst, reg_acc, mod_acc, omw, m);
    k_finalize<<<1, 1, 0, stream>>>(H_acc, reg_acc, mod_acc, out + (size_t)N * Q,
                                    inv_m, inv_N, entc);
  } else {
    // ---------------- Path B: gather + edges (round-2 structure, improved) ----------------
    float* lt   = (float*)d_ws;                    // E*Q
    float* ni   = lt + (size_t)E * Q;              // N*Q
    float* S    = ni + (size_t)N * Q;              // 11*Q
    float* H_acc   = S + 11 * Q;
    float* reg_acc = H_acc + 1;
    float* mod_acc = H_acc + 2;
    int* row_ptr = (int*)(H_acc + 3);              // N+1
    int* cursor  = row_ptr + (N + 1);              // N
    int* eid     = cursor + N;                     // E

    hipMemsetAsync(S, 0, (size_t)(11 * Q + 3) * sizeof(float), stream);
    hipMemsetAsync(cursor, 0, (size_t)N * sizeof(int), stream);

    k_count<<<gridE, TPB, 0, stream>>>(dst, cursor, E);
    k_scan<<<1, 1024, 0, stream>>>(cursor, row_ptr, N);
    k_fill_eid<<<gridE, TPB, 0, stream>>>(dst, cursor, eid, E);
    k_init_edges<<<gridE, TPB, 0, stream>>>(msg_init, beta, lt, E);
    k_init_nodes<<<gridN, TPB, 0, stream>>>(psi_init, S, N);

    for (int t = 0; t < 10; ++t) {
      k_gatherB<<<gridF, TPB, 0, stream>>>(row_ptr, eid, lt, beta,
                                           S + t * Q, S + (t + 1) * Q,
                                           ni, out, neg_mw, N, (t == 9) ? 1 : 0);
      if (t < 9) {
        k_edges<<<gridM, TPB, 0, stream>>>(src, dst, beta, ni, lt,
                                           S + t * Q, neg_mw, m);
      }
    }

    k_entropy<<<gridN, TPB, 0, stream>>>(out, H_acc, N);
    k_edge_stats<<<gridS, TPB, 0, stream>>>(out, src, dst, reg_acc, mod_acc, omw, m);
    k_finalize<<<1, 1, 0, stream>>>(H_acc, reg_acc, mod_acc, out + (size_t)N * Q,
                                    inv_m, inv_N, entc);
  }
}

// Round 4
// 1164.218 us; speedup vs baseline: 6.7431x; 1.0005x over previous
//
#include <hip/hip_runtime.h>
#include <hip/hip_fp16.h>
#include <math.h>

#define Q 8
#define TPB 256
#define WPB (TPB / 64)     // waves per block
#define SCAN_T 1024

struct alignas(16) H8 { __half h[8]; };

// ---------- helpers ----------

__device__ __forceinline__ void load8(const float* __restrict__ p, float r[Q]) {
  const float4* p4 = reinterpret_cast<const float4*>(p);
  float4 a = p4[0], b = p4[1];
  r[0]=a.x; r[1]=a.y; r[2]=a.z; r[3]=a.w;
  r[4]=b.x; r[5]=b.y; r[6]=b.z; r[7]=b.w;
}

__device__ __forceinline__ void load8h(const __half* __restrict__ p, float r[Q]) {
  H8 t = *reinterpret_cast<const H8*>(p);
#pragma unroll
  for (int j=0;j<Q;j++) r[j] = __half2float(t.h[j]);
}

__device__ __forceinline__ void store8h(__half* __restrict__ p, const float r[Q]) {
  H8 t;
#pragma unroll
  for (int j=0;j<Q;j++) t.h[j] = __float2half(r[j]);
  *reinterpret_cast<H8*>(p) = t;
}

__device__ __forceinline__ void softmax8(float x[Q]) {
  float mx = x[0];
#pragma unroll
  for (int j=1;j<Q;j++) mx = fmaxf(mx, x[j]);
  float s = 0.f;
#pragma unroll
  for (int j=0;j<Q;j++) { x[j] = expf(x[j]-mx); s += x[j]; }
  float inv = 1.0f/s;
#pragma unroll
  for (int j=0;j<Q;j++) x[j] *= inv;
}

// softmax across the 8 lanes of a slot (lane = slot*8 + j); returns this lane's prob
__device__ __forceinline__ float softmax8_lanes(float x) {
  float mx = x;
  mx = fmaxf(mx, __shfl_xor(mx, 1));
  mx = fmaxf(mx, __shfl_xor(mx, 2));
  mx = fmaxf(mx, __shfl_xor(mx, 4));
  float ex = expf(x - mx);
  float s = ex;
  s += __shfl_xor(s, 1);
  s += __shfl_xor(s, 2);
  s += __shfl_xor(s, 4);
  return ex / s;
}

__device__ __forceinline__ float wave_sum(float x) {
  x += __shfl_down(x, 32);
  x += __shfl_down(x, 16);
  x += __shfl_down(x, 8);
  x += __shfl_down(x, 4);
  x += __shfl_down(x, 2);
  x += __shfl_down(x, 1);
  return x;
}

__device__ __forceinline__ void block_reduce_atomic(float x, float* target, float* lds) {
  float w = wave_sum(x);
  const int lane = threadIdx.x & 63, wid = threadIdx.x >> 6;
  if (lane == 0) lds[wid] = w;
  __syncthreads();
  if (threadIdx.x == 0) {
    float t = 0.f;
#pragma unroll
    for (int i = 0; i < WPB; i++) t += lds[i];
    atomicAdd(target, t);
  }
  __syncthreads();
}

// ---------- CSR build ----------

__global__ void k_count(const int* __restrict__ dst, int* __restrict__ cnt, int E) {
  int e = blockIdx.x * TPB + threadIdx.x;
  if (e < E) atomicAdd(&cnt[dst[e]], 1);
}

// block-local exclusive scan; row_ptr gets local-exclusive, bsum gets block total
__global__ void k_scan1(const int* __restrict__ cnt, int* __restrict__ row_ptr,
                        int* __restrict__ bsum, int N) {
  __shared__ int lds[SCAN_T];
  const int tid = threadIdx.x;
  const int i = blockIdx.x * SCAN_T + tid;
  int c = (i < N) ? cnt[i] : 0;
  lds[tid] = c;
  __syncthreads();
  for (int off = 1; off < SCAN_T; off <<= 1) {
    int v = (tid >= off) ? lds[tid - off] : 0;
    __syncthreads();
    lds[tid] += v;
    __syncthreads();
  }
  if (i < N) row_ptr[i] = lds[tid] - c;
  if (tid == SCAN_T - 1) bsum[blockIdx.x] = lds[tid];
}

// single block: exclusive scan of nb block sums -> boffs; row_ptr[N] = total
__global__ void k_scan2(const int* __restrict__ bsum, int* __restrict__ boffs,
                        int* __restrict__ row_ptr, int nb, int N) {
  __shared__ int lds[SCAN_T];
  const int tid = threadIdx.x;
  int v = (tid < nb) ? bsum[tid] : 0;
  lds[tid] = v;
  __syncthreads();
  for (int off = 1; off < SCAN_T; off <<= 1) {
    int t = (tid >= off) ? lds[tid - off] : 0;
    __syncthreads();
    lds[tid] += t;
    __syncthreads();
  }
  if (tid < nb) boffs[tid] = lds[tid] - v;
  if (tid == 0) row_ptr[N] = lds[nb - 1];
}

__global__ void k_scan3(int* __restrict__ row_ptr, int* __restrict__ cursor,
                        const int* __restrict__ boffs, int N) {
  int i = blockIdx.x * SCAN_T + threadIdx.x;
  if (i < N) {
    int r = row_ptr[i] + boffs[blockIdx.x];
    row_ptr[i] = r;
    cursor[i] = r;
  }
}

__global__ void k_fill_pos_eid(const int* __restrict__ dst, int* __restrict__ cursor,
                               int* __restrict__ pos, int* __restrict__ eid, int E) {
  int e = blockIdx.x * TPB + threadIdx.x;
  if (e < E) { int p = atomicAdd(&cursor[dst[e]], 1); pos[e] = p; eid[p] = e; }
}

__global__ void k_fill_eid(const int* __restrict__ dst, int* __restrict__ cursor,
                           int* __restrict__ eid, int E) {
  int e = blockIdx.x * TPB + threadIdx.x;
  if (e < E) { int p = atomicAdd(&cursor[dst[e]], 1); eid[p] = e; }
}

// contiguous write; random read of pos (6.4MB, mostly L2)
__global__ void k_revp_pos(const int* __restrict__ eid, const int* __restrict__ pos,
                           int* __restrict__ revp, int E, int m) {
  int p = blockIdx.x * TPB + threadIdx.x;
  if (p < E) {
    int e = eid[p];
    int re = (e < m) ? e + m : e - m;
    revp[p] = pos[re];
  }
}

// ---------- init ----------

__global__ void k_init_edges_posA(const float* __restrict__ msg_init,
                                  const int* __restrict__ pos,
                                  const float* __restrict__ beta,
                                  __half* __restrict__ ltA, int E) {
  int e = blockIdx.x * TPB + threadIdx.x;
  if (e >= E) return;
  float b  = beta[0];
  float ew = expf(b) - 1.0f;
  float r[Q];
  load8(msg_init + (size_t)e * Q, r);
  float s = 0.f;
#pragma unroll
  for (int j=0;j<Q;j++) s += r[j];
  float inv = 1.0f / s;
#pragma unroll
  for (int j=0;j<Q;j++) r[j] = log1pf(r[j] * inv * ew);
  store8h(ltA + (size_t)pos[e] * Q, r);
}

__global__ void k_init_edgesB(const float* __restrict__ msg_init,
                              const float* __restrict__ beta,
                              __half* __restrict__ lt, int E) {
  int e = blockIdx.x * TPB + threadIdx.x;
  if (e >= E) return;
  float b  = beta[0];
  float ew = expf(b) - 1.0f;
  float r[Q];
  load8(msg_init + (size_t)e * Q, r);
  float s = 0.f;
#pragma unroll
  for (int j=0;j<Q;j++) s += r[j];
  float inv = 1.0f / s;
#pragma unroll
  for (int j=0;j<Q;j++) r[j] = log1pf(r[j] * inv * ew);
  store8h(lt + (size_t)e * Q, r);
}

__global__ void k_init_nodes(const float* __restrict__ psi_init,
                             float* __restrict__ S0, int N) {
  __shared__ float lds[WPB];
  int n = blockIdx.x * TPB + threadIdx.x;
  float p[Q];
  if (n < N) {
    load8(psi_init + (size_t)n * Q, p);
    float s = 0.f;
#pragma unroll
    for (int j=0;j<Q;j++) s += p[j];
    float inv = 1.0f / s;
#pragma unroll
    for (int j=0;j<Q;j++) p[j] *= inv;
  } else {
#pragma unroll
    for (int j=0;j<Q;j++) p[j] = 0.f;
  }
#pragma unroll
  for (int j=0;j<Q;j++) {
    block_reduce_atomic(p[j], &S0[j], lds);
  }
}

// ---------- Path A: fused per-node iteration (fp16 lt) ----------
__global__ void k_fused(const int* __restrict__ row_ptr,
                        const int* __restrict__ revp,
                        const __half* __restrict__ ltA,
                        __half* __restrict__ ltB,
                        const float* __restrict__ beta,
                        const float* __restrict__ S,
                        float* __restrict__ S_nxt,
                        float neg_mw, int N) {
  __shared__ float part[WPB][Q];
  const int lane = threadIdx.x & 63;
  const int wid  = threadIdx.x >> 6;
  const int slot = lane >> 3;
  const int j    = lane & 7;
  const float b  = beta[0];
  const float ew = expf(b) - 1.0f;
  const float h  = neg_mw * b * S[j];
  float sacc = 0.f;

  const int wg = blockIdx.x * WPB + wid;
  const int ws = gridDim.x * WPB;
  for (int u = wg; u < N; u += ws) {
    const int s = row_ptr[u], e = row_ptr[u + 1];
    float acc = 0.f;
    for (int r = s + slot; r < e; r += 8) acc += __half2float(ltA[(size_t)r * Q + j]);
    acc += __shfl_xor(acc, 8);
    acc += __shfl_xor(acc, 16);
    acc += __shfl_xor(acc, 32);
    const float x = acc + h;                 // ni[u][j] + h[j]
    float p = softmax8_lanes(x);             // psi_{t+1}[u][j]
    if (slot == 0) sacc += p;
    for (int r = s + slot; r < e; r += 8) {
      float v = __half2float(ltA[(size_t)r * Q + j]);   // L1-hot reload
      float pm = softmax8_lanes(x - v);      // new msg on edge rev(r)
      float o = log1pf(pm * ew);
      ltB[(size_t)revp[r] * Q + j] = __float2half(o);   // 16B scattered per slot
    }
  }
  if (slot == 0) part[wid][j] = sacc;
  __syncthreads();
  if (threadIdx.x < Q) {
    float tot = 0.f;
#pragma unroll
    for (int w = 0; w < WPB; w++) tot += part[w][threadIdx.x];
    atomicAdd(&S_nxt[threadIdx.x], tot);
  }
}

// Final psi + fused entropy accumulation.
__global__ void k_psi_out_ent(const int* __restrict__ row_ptr,
                              const __half* __restrict__ ltA,
                              const float* __restrict__ beta,
                              const float* __restrict__ S,
                              float neg_mw, float* __restrict__ psi,
                              float* __restrict__ H_acc, int N) {
  __shared__ float lds[WPB];
  const int lane = threadIdx.x & 63;
  const int wid  = threadIdx.x >> 6;
  const int slot = lane >> 3;
  const int j    = lane & 7;
  const float h  = neg_mw * beta[0] * S[j];
  float hacc = 0.f;
  const int wg = blockIdx.x * WPB + wid;
  const int ws = gridDim.x * WPB;
  for (int u = wg; u < N; u += ws) {
    const int s = row_ptr[u], e = row_ptr[u + 1];
    float acc = 0.f;
    for (int r = s + slot; r < e; r += 8) acc += __half2float(ltA[(size_t)r * Q + j]);
    acc += __shfl_xor(acc, 8);
    acc += __shfl_xor(acc, 16);
    acc += __shfl_xor(acc, 32);
    float p = softmax8_lanes(acc + h);
    if (slot == 0) {
      psi[(size_t)u * Q + j] = p;
      float el = p * logf(p + 1e-12f);
      el += __shfl_xor(el, 1);
      el += __shfl_xor(el, 2);
      el += __shfl_xor(el, 4);
      if (j == 0) hacc += el;
    }
  }
  block_reduce_atomic(hacc, H_acc, lds);
}

// ---------- Path B (fallback, fp16): gather + edges ----------

__global__ void k_gatherB(const int* __restrict__ row_ptr,
                          const int* __restrict__ eid,
                          const __half* __restrict__ lt,
                          const float* __restrict__ beta,
                          const float* __restrict__ S,
                          float* __restrict__ S_nxt,
                          float* __restrict__ ni,
                          float* __restrict__ psi_out,
                          float neg_mw, int N, int storePsi) {
  __shared__ float part[WPB][Q];
  const int lane = threadIdx.x & 63;
  const int wid  = threadIdx.x >> 6;
  const int slot = lane >> 3;
  const int j    = lane & 7;
  const float h  = neg_mw * beta[0] * S[j];
  float sacc = 0.f;
  const int wg = blockIdx.x * WPB + wid;
  const int ws = gridDim.x * WPB;
  for (int u = wg; u < N; u += ws) {
    const int s = row_ptr[u], e = row_ptr[u + 1];
    float acc = 0.f;
    for (int r = s + slot; r < e; r += 8)
      acc += __half2float(lt[(size_t)eid[r] * Q + j]);
    acc += __shfl_xor(acc, 8);
    acc += __shfl_xor(acc, 16);
    acc += __shfl_xor(acc, 32);
    if (slot == 0) ni[(size_t)u * Q + j] = acc;
    float p = softmax8_lanes(acc + h);
    if (slot == 0) {
      sacc += p;
      if (storePsi) psi_out[(size_t)u * Q + j] = p;
    }
  }
  if (slot == 0) part[wid][j] = sacc;
  __syncthreads();
  if (threadIdx.x < Q) {
    float tot = 0.f;
#pragma unroll
    for (int w = 0; w < WPB; w++) tot += part[w][threadIdx.x];
    atomicAdd(&S_nxt[threadIdx.x], tot);
  }
}

__global__ void k_edgesB(const int* __restrict__ src, const int* __restrict__ dst,
                         const float* __restrict__ beta,
                         const float* __restrict__ ni,
                         __half* __restrict__ lt,
                         const float* __restrict__ S,
                         float neg_mw, int m) {
  int i = blockIdx.x * TPB + threadIdx.x;
  if (i >= m) return;
  float b  = beta[0];
  float ew = expf(b) - 1.0f;
  float hb = neg_mw * b;
  float h[Q];
#pragma unroll
  for (int j=0;j<Q;j++) h[j] = hb * S[j];

  int u = src[i], v = dst[i];
  float lti[Q], ltr[Q], niu[Q], niv[Q];
  load8h(lt + (size_t)i * Q, lti);
  load8h(lt + ((size_t)i + (size_t)m) * Q, ltr);
  load8(ni + (size_t)u * Q, niu);
  load8(ni + (size_t)v * Q, niv);

  float a0[Q], a1[Q];
#pragma unroll
  for (int j=0;j<Q;j++) a0[j] = niu[j] - ltr[j] + h[j];
#pragma unroll
  for (int j=0;j<Q;j++) a1[j] = niv[j] - lti[j] + h[j];
  softmax8(a0);
  softmax8(a1);
#pragma unroll
  for (int j=0;j<Q;j++) { a0[j] = log1pf(a0[j] * ew); a1[j] = log1pf(a1[j] * ew); }
  store8h(lt + (size_t)i * Q, a0);
  store8h(lt + ((size_t)i + (size_t)m) * Q, a1);
}

__global__ void k_entropy(const float* __restrict__ psi,
                          float* __restrict__ H_acc, int N) {
  __shared__ float lds[WPB];
  float s = 0.f;
  for (int n = blockIdx.x * TPB + threadIdx.x; n < N; n += gridDim.x * TPB) {
    float p[Q];
    load8(psi + (size_t)n * Q, p);
#pragma unroll
    for (int j=0;j<Q;j++) s += p[j] * logf(p[j] + 1e-12f);
  }
  block_reduce_atomic(s, H_acc, lds);
}

// ---------- stats ----------

__global__ void k_edge_stats(const float* __restrict__ psi,
                             const int* __restrict__ src,
                             const int* __restrict__ dst,
                             float* __restrict__ reg_acc,
                             float* __restrict__ mod_acc,
                             float one_minus_mw, int m) {
  __shared__ float lds1[WPB];
  __shared__ float lds2[WPB];
  float reg = 0.f, mod = 0.f;
  for (int i = blockIdx.x * TPB + threadIdx.x; i < m; i += gridDim.x * TPB) {
    int u = src[i], v = dst[i];
    float pu[Q], pv[Q];
    load8(psi + (size_t)u * Q, pu);
    load8(psi + (size_t)v * Q, pv);
#pragma unroll
    for (int j=0;j<Q;j++) { float d = pu[j] - pv[j]; reg += d * d; }
    int au = 0, av = 0;
    float mu = pu[0], mv = pv[0];
#pragma unroll
    for (int j=1;j<Q;j++) {
      if (pu[j] > mu) { mu = pu[j]; au = j; }
      if (pv[j] > mv) { mv = pv[j]; av = j; }
    }
    if (au == av) mod += one_minus_mw;
  }
  block_reduce_atomic(reg, reg_acc, lds1);
  block_reduce_atomic(mod, mod_acc, lds2);
}

__global__ void k_finalize(const float* __restrict__ H_acc,
                           const float* __restrict__ reg_acc,
                           const float* __restrict__ mod_acc,
                           float* __restrict__ out3,
                           float inv_m, float inv_N, float entc) {
  out3[0] = reg_acc[0] * inv_m;
  out3[1] = (-H_acc[0] * inv_N) * entc;
  out3[2] = mod_acc[0] * inv_m;
}

// ---------- host ----------

extern "C" void kernel_launch(void* const* d_in, const int* in_sizes, int n_in,
                              void* d_out, int out_size, void* d_ws, size_t ws_size,
                              hipStream_t stream) {
  const float* msg_init = (const float*)d_in[0];
  const float* psi_init = (const float*)d_in[1];
  const float* beta     = (const float*)d_in[2];
  const int*   src      = (const int*)d_in[3];
  const int*   dst      = (const int*)d_in[4];

  const int E = in_sizes[3];
  const int m = E / 2;
  const int N = in_sizes[1] / Q;
  const double mean_w = (double)E / ((double)N * (double)N);
  const float  neg_mw = (float)(-mean_w);

  float* out = (float*)d_out;

  const int gridE = (E + TPB - 1) / TPB;
  const int gridM = (m + TPB - 1) / TPB;
  const int gridN = (N + TPB - 1) / TPB;
  const int gridF = min(1024, (N + WPB - 1) / WPB);
  const int gridS = min(512, gridM);
  const int nb    = (N + SCAN_T - 1) / SCAN_T;   // scan blocks (<=1024)

  const float entc  = (float)(4.0 * log(0.5) / log(1.0 / (double)Q));
  const float inv_m = (float)(1.0 / (double)m);
  const float inv_N = (float)(1.0 / (double)N);
  const float omw   = (float)(1.0 - mean_w);

  // Path A footprint
  size_t needA = (size_t)2 * E * Q * sizeof(__half)       // ltA, ltB
               + (size_t)3 * E * sizeof(int)              // revp, eid, pos
               + (size_t)(2 * N + 1) * sizeof(int)        // row_ptr, cursor
               + (size_t)2 * SCAN_T * sizeof(int)         // bsum, boffs
               + (size_t)(11 * Q + 3) * sizeof(float) + 1024;

  if (ws_size >= needA) {
    // ---------------- Path A ----------------
    __half* ltA = (__half*)d_ws;                       // E*Q
    __half* ltB = ltA + (size_t)E * Q;                 // E*Q
    int* revp    = (int*)(ltB + (size_t)E * Q);        // E
    int* eid     = revp + E;                           // E
    int* pos     = eid + E;                            // E
    int* row_ptr = pos + E;                            // N+1
    int* cursor  = row_ptr + (N + 1);                  // N
    int* bsum    = cursor + N;                         // SCAN_T
    int* boffs   = bsum + SCAN_T;                      // SCAN_T
    float* S     = (float*)(boffs + SCAN_T);           // 11*Q
    float* H_acc   = S + 11 * Q;
    float* reg_acc = H_acc + 1;
    float* mod_acc = H_acc + 2;

    hipMemsetAsync(cursor, 0, (size_t)N * sizeof(int), stream);
    hipMemsetAsync(S, 0, (size_t)(11 * Q + 3) * sizeof(float), stream);

    k_count<<<gridE, TPB, 0, stream>>>(dst, cursor, E);
    k_scan1<<<nb, SCAN_T, 0, stream>>>(cursor, row_ptr, bsum, N);
    k_scan2<<<1, SCAN_T, 0, stream>>>(bsum, boffs, row_ptr, nb, N);
    k_scan3<<<nb, SCAN_T, 0, stream>>>(row_ptr, cursor, boffs, N);
    k_fill_pos_eid<<<gridE, TPB, 0, stream>>>(dst, cursor, pos, eid, E);
    k_revp_pos<<<gridE, TPB, 0, stream>>>(eid, pos, revp, E, m);
    k_init_edges_posA<<<gridE, TPB, 0, stream>>>(msg_init, pos, beta, ltA, E);
    k_init_nodes<<<gridN, TPB, 0, stream>>>(psi_init, S, N);

    __half* cur = ltA;
    __half* nxt = ltB;
    for (int t = 0; t < 9; ++t) {
      k_fused<<<gridF, TPB, 0, stream>>>(row_ptr, revp, cur, nxt, beta,
                                         S + t * Q, S + (t + 1) * Q, neg_mw, N);
      __half* tmp = cur; cur = nxt; nxt = tmp;
    }
    k_psi_out_ent<<<gridF, TPB, 0, stream>>>(row_ptr, cur, beta, S + 9 * Q,
                                             neg_mw, out, H_acc, N);

    k_edge_stats<<<gridS, TPB, 0, stream>>>(out, src, dst, reg_acc, mod_acc, omw, m);
    k_finalize<<<1, 1, 0, stream>>>(H_acc, reg_acc, mod_acc, out + (size_t)N * Q,
                                    inv_m, inv_N, entc);
  } else {
    // ---------------- Path B ----------------
    __half* lt  = (__half*)d_ws;                       // E*Q
    float* ni   = (float*)(lt + (size_t)E * Q);        // N*Q
    int* eid     = (int*)(ni + (size_t)N * Q);         // E
    int* row_ptr = eid + E;                            // N+1
    int* cursor  = row_ptr + (N + 1);                  // N
    int* bsum    = cursor + N;                         // SCAN_T
    int* boffs   = bsum + SCAN_T;                      // SCAN_T
    float* S     = (float*)(boffs + SCAN_T);           // 11*Q
    float* H_acc   = S + 11 * Q;
    float* reg_acc = H_acc + 1;
    float* mod_acc = H_acc + 2;

    hipMemsetAsync(cursor, 0, (size_t)N * sizeof(int), stream);
    hipMemsetAsync(S, 0, (size_t)(11 * Q + 3) * sizeof(float), stream);

    k_count<<<gridE, TPB, 0, stream>>>(dst, cursor, E);
    k_scan1<<<nb, SCAN_T, 0, stream>>>(cursor, row_ptr, bsum, N);
    k_scan2<<<1, SCAN_T, 0, stream>>>(bsum, boffs, row_ptr, nb, N);
    k_scan3<<<nb, SCAN_T, 0, stream>>>(row_ptr, cursor, boffs, N);
    k_fill_eid<<<gridE, TPB, 0, stream>>>(dst, cursor, eid, E);
    k_init_edgesB<<<gridE, TPB, 0, stream>>>(msg_init, beta, lt, E);
    k_init_nodes<<<gridN, TPB, 0, stream>>>(psi_init, S, N);

    for (int t = 0; t < 10; ++t) {
      k_gatherB<<<gridF, TPB, 0, stream>>>(row_ptr, eid, lt, beta,
                                           S + t * Q, S + (t + 1) * Q,
                                           ni, out, neg_mw, N, (t == 9) ? 1 : 0);
      if (t < 9) {
        k_edgesB<<<gridM, TPB, 0, stream>>>(src, dst, beta, ni, lt,
                                            S + t * Q, neg_mw, m);
      }
    }

    k_entropy<<<gridN, TPB, 0, stream>>>(out, H_acc, N);
    k_edge_stats<<<gridS, TPB, 0, stream>>>(out, src, dst, reg_acc, mod_acc, omw, m);
    k_finalize<<<1, 1, 0, stream>>>(H_acc, reg_acc, mod_acc, out + (size_t)N * Q,
                                    inv_m, inv_N, entc);
  }
}

// Round 5
// 960.433 us; speedup vs baseline: 8.1739x; 1.2122x over previous
//
#include <hip/hip_runtime.h>
#include <hip/hip_fp16.h>
#include <math.h>

#define Q 8
#define TPB 256
#define WPB (TPB / 64)     // waves per block
#define SCAN_T 1024

struct alignas(16) H8 { __half h[8]; };

// ---------- helpers ----------

__device__ __forceinline__ void load8(const float* __restrict__ p, float r[Q]) {
  const float4* p4 = reinterpret_cast<const float4*>(p);
  float4 a = p4[0], b = p4[1];
  r[0]=a.x; r[1]=a.y; r[2]=a.z; r[3]=a.w;
  r[4]=b.x; r[5]=b.y; r[6]=b.z; r[7]=b.w;
}

__device__ __forceinline__ void store8h(__half* __restrict__ p, const float r[Q]) {
  H8 t;
#pragma unroll
  for (int j=0;j<Q;j++) t.h[j] = __float2half(r[j]);
  *reinterpret_cast<H8*>(p) = t;
}

// softmax across the 8 lanes of an aligned 8-lane group; returns this lane's prob
__device__ __forceinline__ float softmax8_lanes(float x) {
  float mx = x;
  mx = fmaxf(mx, __shfl_xor(mx, 1));
  mx = fmaxf(mx, __shfl_xor(mx, 2));
  mx = fmaxf(mx, __shfl_xor(mx, 4));
  float ex = expf(x - mx);
  float s = ex;
  s += __shfl_xor(s, 1);
  s += __shfl_xor(s, 2);
  s += __shfl_xor(s, 4);
  return ex / s;
}

__device__ __forceinline__ float wave_sum(float x) {
  x += __shfl_down(x, 32);
  x += __shfl_down(x, 16);
  x += __shfl_down(x, 8);
  x += __shfl_down(x, 4);
  x += __shfl_down(x, 2);
  x += __shfl_down(x, 1);
  return x;
}

__device__ __forceinline__ void block_reduce_atomic(float x, float* target, float* lds) {
  float w = wave_sum(x);
  const int lane = threadIdx.x & 63, wid = threadIdx.x >> 6;
  if (lane == 0) lds[wid] = w;
  __syncthreads();
  if (threadIdx.x == 0) {
    float t = 0.f;
#pragma unroll
    for (int i = 0; i < WPB; i++) t += lds[i];
    atomicAdd(target, t);
  }
  __syncthreads();
}

// ---------- CSR build ----------

// count + local rank in one pass (pos[e] = rank of e within its dst bucket)
__global__ void k_count_pos(const int* __restrict__ dst, int* __restrict__ cnt,
                            int* __restrict__ pos, int E) {
  int e = blockIdx.x * TPB + threadIdx.x;
  if (e < E) pos[e] = atomicAdd(&cnt[dst[e]], 1);
}

// block-local exclusive scan; row_ptr gets local-exclusive, bsum gets block total
__global__ void k_scan1(const int* __restrict__ cnt, int* __restrict__ row_ptr,
                        int* __restrict__ bsum, int N) {
  __shared__ int lds[SCAN_T];
  const int tid = threadIdx.x;
  const int i = blockIdx.x * SCAN_T + tid;
  int c = (i < N) ? cnt[i] : 0;
  lds[tid] = c;
  __syncthreads();
  for (int off = 1; off < SCAN_T; off <<= 1) {
    int v = (tid >= off) ? lds[tid - off] : 0;
    __syncthreads();
    lds[tid] += v;
    __syncthreads();
  }
  if (i < N) row_ptr[i] = lds[tid] - c;
  if (tid == SCAN_T - 1) bsum[blockIdx.x] = lds[tid];
}

__global__ void k_scan2(const int* __restrict__ bsum, int* __restrict__ boffs,
                        int* __restrict__ row_ptr, int nb, int N) {
  __shared__ int lds[SCAN_T];
  const int tid = threadIdx.x;
  int v = (tid < nb) ? bsum[tid] : 0;
  lds[tid] = v;
  __syncthreads();
  for (int off = 1; off < SCAN_T; off <<= 1) {
    int t = (tid >= off) ? lds[tid - off] : 0;
    __syncthreads();
    lds[tid] += t;
    __syncthreads();
  }
  if (tid < nb) boffs[tid] = lds[tid] - v;
  if (tid == 0) row_ptr[N] = lds[nb - 1];
}

__global__ void k_scan3(int* __restrict__ row_ptr, const int* __restrict__ boffs, int N) {
  int i = blockIdx.x * SCAN_T + threadIdx.x;
  if (i < N) row_ptr[i] += boffs[blockIdx.x];
}

// pos[e] += row_ptr[dst[e]]  (local rank -> global CSR position)
__global__ void k_fixup(const int* __restrict__ dst, const int* __restrict__ row_ptr,
                        int* __restrict__ pos, int E) {
  int e = blockIdx.x * TPB + threadIdx.x;
  if (e < E) pos[e] += row_ptr[dst[e]];
}

// per edge pair: write rn = {rev CSR pos, neighbor(src) id} and scatter initial
// normalized logterm into CSR order.
__global__ void k_rn_init(const int* __restrict__ src, const int* __restrict__ dst,
                          const int* __restrict__ pos,
                          const float* __restrict__ msg_init,
                          const float* __restrict__ beta,
                          int2* __restrict__ rn, __half* __restrict__ ltA,
                          int E, int m) {
  int i = blockIdx.x * TPB + threadIdx.x;
  if (i >= m) return;
  const float b  = beta[0];
  const float ew = expf(b) - 1.0f;
  const int u = src[i], v = dst[i];
  const int pu = pos[i];        // position of edge i   (u -> v), in v's segment
  const int pv = pos[i + m];    // position of edge i+m (v -> u), in u's segment
  int2 a; a.x = pv; a.y = u;    // at pu: rev-edge position pv, neighbor u
  int2 c; c.x = pu; c.y = v;    // at pv: rev-edge position pu, neighbor v
  rn[pu] = a;
  rn[pv] = c;

  float r0[Q], r1[Q];
  load8(msg_init + (size_t)i * Q, r0);
  load8(msg_init + ((size_t)i + (size_t)m) * Q, r1);
  float s0 = 0.f, s1 = 0.f;
#pragma unroll
  for (int j=0;j<Q;j++) { s0 += r0[j]; s1 += r1[j]; }
  float i0 = 1.0f / s0, i1 = 1.0f / s1;
#pragma unroll
  for (int j=0;j<Q;j++) { r0[j] = log1pf(r0[j] * i0 * ew); r1[j] = log1pf(r1[j] * i1 * ew); }
  store8h(ltA + (size_t)pu * Q, r0);
  store8h(ltA + (size_t)pv * Q, r1);
}

// ---------- init ----------

// ni0[u][j] = sum over u's CSR segment of ltA
__global__ void k_ni0(const int* __restrict__ row_ptr, const __half* __restrict__ ltA,
                      float* __restrict__ ni0, int N) {
  const int lane = threadIdx.x & 63;
  const int wid  = threadIdx.x >> 6;
  const int slot = lane >> 3;
  const int j    = lane & 7;
  const int wg = blockIdx.x * WPB + wid;
  const int ws = gridDim.x * WPB;
  for (int u = wg; u < N; u += ws) {
    const int s = row_ptr[u], e = row_ptr[u + 1];
    float acc = 0.f;
    for (int r = s + slot; r < e; r += 8) acc += __half2float(ltA[(size_t)r * Q + j]);
    acc += __shfl_xor(acc, 8);
    acc += __shfl_xor(acc, 16);
    acc += __shfl_xor(acc, 32);
    if (slot == 0) ni0[(size_t)u * Q + j] = acc;
  }
}

__global__ void k_init_nodes(const float* __restrict__ psi_init,
                             float* __restrict__ S0, int N) {
  __shared__ float lds[WPB];
  int n = blockIdx.x * TPB + threadIdx.x;
  float p[Q];
  if (n < N) {
    load8(psi_init + (size_t)n * Q, p);
    float s = 0.f;
#pragma unroll
    for (int j=0;j<Q;j++) s += p[j];
    float inv = 1.0f / s;
#pragma unroll
    for (int j=0;j<Q;j++) p[j] *= inv;
  } else {
#pragma unroll
    for (int j=0;j<Q;j++) p[j] = 0.f;
  }
#pragma unroll
  for (int j=0;j<Q;j++) {
    block_reduce_atomic(p[j], &S0[j], lds);
  }
}

// ---------- per-iteration kernel ----------
// For node u (one wave per node), CSR segment [s,e). Row r = edge (v -> u):
//   new lt[r] = log1p(ew * softmax_j(ni_t[v] + h - lt_t[revpos]))   (contiguous write)
//   ni_{t+1}[u] = sum of new lt over segment                         (register acc)
//   psi_{t+1}[u] = softmax(ni_t[u] + h) -> S_{t+1}                   (block-reduced)
// Scattered READS (lt_t[revpos], ni_t[v]); all writes contiguous/local.
__global__ void k_iter(const int* __restrict__ row_ptr,
                       const int2* __restrict__ rn,
                       const __half* __restrict__ ltIn,
                       __half* __restrict__ ltOut,
                       const float* __restrict__ ni_cur,
                       float* __restrict__ ni_nxt,
                       const float* __restrict__ beta,
                       const float* __restrict__ S,
                       float* __restrict__ S_nxt,
                       float neg_mw, int N) {
  __shared__ float part[WPB][Q];
  const int lane = threadIdx.x & 63;
  const int wid  = threadIdx.x >> 6;
  const int slot = lane >> 3;
  const int j    = lane & 7;
  const float b  = beta[0];
  const float ew = expf(b) - 1.0f;
  const float h  = neg_mw * b * S[j];
  float sacc = 0.f;

  const int wg = blockIdx.x * WPB + wid;
  const int ws = gridDim.x * WPB;
  for (int u = wg; u < N; u += ws) {
    const int s = row_ptr[u], e = row_ptr[u + 1];
    float acc = 0.f;
    int r = s + slot;
    int2 w;
    if (r < e) w = rn[r];
    while (r < e) {
      const int r2 = r + 8;
      int2 w2;
      if (r2 < e) w2 = rn[r2];                                   // prefetch next row's meta
      const float vin = __half2float(ltIn[(size_t)w.x * Q + j]); // scattered 16B read
      const float xv  = ni_cur[(size_t)w.y * Q + j] + h;         // L2-resident read
      const float pm  = softmax8_lanes(xv - vin);                // new msg on edge (v->u)
      const float o   = log1pf(pm * ew);
      ltOut[(size_t)r * Q + j] = __float2half(o);                // contiguous write
      acc += o;
      r = r2; w = w2;
    }
    // ni_{t+1}[u]
    acc += __shfl_xor(acc, 8);
    acc += __shfl_xor(acc, 16);
    acc += __shfl_xor(acc, 32);
    if (slot == 0) {
      ni_nxt[(size_t)u * Q + j] = acc;
      // psi_{t+1}[u] for S_{t+1}
      float x = ni_cur[(size_t)u * Q + j] + h;
      sacc += softmax8_lanes(x);
    }
  }
  if (slot == 0) part[wid][j] = sacc;
  __syncthreads();
  if (threadIdx.x < Q) {
    float tot = 0.f;
#pragma unroll
    for (int w = 0; w < WPB; w++) tot += part[w][threadIdx.x];
    atomicAdd(&S_nxt[threadIdx.x], tot);
  }
}

// ---------- finalization ----------

// psi = softmax(ni9 + h9) -> out; fused entropy accumulation. 8 lanes per node.
__global__ void k_psi_ent(const float* __restrict__ ni,
                          const float* __restrict__ beta,
                          const float* __restrict__ S,
                          float neg_mw, float* __restrict__ psi,
                          float* __restrict__ H_acc, int N) {
  __shared__ float lds[WPB];
  const int j = threadIdx.x & 7;
  const float h = neg_mw * beta[0] * S[j];
  float hacc = 0.f;
  const int g0 = (blockIdx.x * TPB + threadIdx.x) >> 3;
  const int gs = (gridDim.x * TPB) >> 3;
  for (int n = g0; n < N; n += gs) {
    float p = softmax8_lanes(ni[(size_t)n * Q + j] + h);
    psi[(size_t)n * Q + j] = p;
    float el = p * logf(p + 1e-12f);
    el += __shfl_xor(el, 1);
    el += __shfl_xor(el, 2);
    el += __shfl_xor(el, 4);
    if (j == 0) hacc += el;
  }
  block_reduce_atomic(hacc, H_acc, lds);
}

__global__ void k_edge_stats(const float* __restrict__ psi,
                             const int* __restrict__ src,
                             const int* __restrict__ dst,
                             float* __restrict__ reg_acc,
                             float* __restrict__ mod_acc,
                             float one_minus_mw, int m) {
  __shared__ float lds1[WPB];
  __shared__ float lds2[WPB];
  float reg = 0.f, mod = 0.f;
  for (int i = blockIdx.x * TPB + threadIdx.x; i < m; i += gridDim.x * TPB) {
    int u = src[i], v = dst[i];
    float pu[Q], pv[Q];
    load8(psi + (size_t)u * Q, pu);
    load8(psi + (size_t)v * Q, pv);
#pragma unroll
    for (int j=0;j<Q;j++) { float d = pu[j] - pv[j]; reg += d * d; }
    int au = 0, av = 0;
    float mu = pu[0], mv = pv[0];
#pragma unroll
    for (int j=1;j<Q;j++) {
      if (pu[j] > mu) { mu = pu[j]; au = j; }
      if (pv[j] > mv) { mv = pv[j]; av = j; }
    }
    if (au == av) mod += one_minus_mw;
  }
  block_reduce_atomic(reg, reg_acc, lds1);
  block_reduce_atomic(mod, mod_acc, lds2);
}

__global__ void k_finalize(const float* __restrict__ H_acc,
                           const float* __restrict__ reg_acc,
                           const float* __restrict__ mod_acc,
                           float* __restrict__ out3,
                           float inv_m, float inv_N, float entc) {
  out3[0] = reg_acc[0] * inv_m;
  out3[1] = (-H_acc[0] * inv_N) * entc;
  out3[2] = mod_acc[0] * inv_m;
}

// ---------- host ----------

extern "C" void kernel_launch(void* const* d_in, const int* in_sizes, int n_in,
                              void* d_out, int out_size, void* d_ws, size_t ws_size,
                              hipStream_t stream) {
  const float* msg_init = (const float*)d_in[0];
  const float* psi_init = (const float*)d_in[1];
  const float* beta     = (const float*)d_in[2];
  const int*   src      = (const int*)d_in[3];
  const int*   dst      = (const int*)d_in[4];

  const int E = in_sizes[3];
  const int m = E / 2;
  const int N = in_sizes[1] / Q;
  const double mean_w = (double)E / ((double)N * (double)N);
  const float  neg_mw = (float)(-mean_w);

  float* out = (float*)d_out;

  // ---- workspace layout ----
  __half* ltA = (__half*)d_ws;                      // E*Q halves
  __half* ltB = ltA + (size_t)E * Q;                // E*Q halves
  int2*  rn   = (int2*)(ltB + (size_t)E * Q);       // E int2
  int*   pos  = (int*)(rn + E);                     // E
  int*   row_ptr = pos + E;                         // N+1
  int*   cnt     = row_ptr + (N + 1);               // N
  int*   bsum    = cnt + N;                         // SCAN_T
  int*   boffs   = bsum + SCAN_T;                   // SCAN_T
  float* ni0     = (float*)(boffs + SCAN_T);        // N*Q
  float* ni1     = ni0 + (size_t)N * Q;             // N*Q
  float* S       = ni1 + (size_t)N * Q;             // 11*Q
  float* H_acc   = S + 11 * Q;
  float* reg_acc = H_acc + 1;
  float* mod_acc = H_acc + 2;

  const int gridE = (E + TPB - 1) / TPB;
  const int gridM = (m + TPB - 1) / TPB;
  const int gridN = (N + TPB - 1) / TPB;
  const int gridI = min(2048, (N + WPB - 1) / WPB);   // iteration kernel
  const int gridS = min(512, gridM);
  const int nb    = (N + SCAN_T - 1) / SCAN_T;

  const float entc  = (float)(4.0 * log(0.5) / log(1.0 / (double)Q));
  const float inv_m = (float)(1.0 / (double)m);
  const float inv_N = (float)(1.0 / (double)N);
  const float omw   = (float)(1.0 - mean_w);

  hipMemsetAsync(cnt, 0, (size_t)N * sizeof(int), stream);
  hipMemsetAsync(S, 0, (size_t)(11 * Q + 3) * sizeof(float), stream);

  // CSR build (atomic rank fused into count; no separate fill)
  k_count_pos<<<gridE, TPB, 0, stream>>>(dst, cnt, pos, E);
  k_scan1<<<nb, SCAN_T, 0, stream>>>(cnt, row_ptr, bsum, N);
  k_scan2<<<1, SCAN_T, 0, stream>>>(bsum, boffs, row_ptr, nb, N);
  k_scan3<<<nb, SCAN_T, 0, stream>>>(row_ptr, boffs, N);
  k_fixup<<<gridE, TPB, 0, stream>>>(dst, row_ptr, pos, E);
  k_rn_init<<<gridM, TPB, 0, stream>>>(src, dst, pos, msg_init, beta, rn, ltA, E, m);
  k_ni0<<<gridI, TPB, 0, stream>>>(row_ptr, ltA, ni0, N);
  k_init_nodes<<<gridN, TPB, 0, stream>>>(psi_init, S, N);

  // 9 fused iterations: produce lt_{t+1}, ni_{t+1}, S_{t+1}
  __half* lcur = ltA; __half* lnxt = ltB;
  float*  ncur = ni0; float*  nnxt = ni1;
  for (int t = 0; t < 9; ++t) {
    k_iter<<<gridI, TPB, 0, stream>>>(row_ptr, rn, lcur, lnxt, ncur, nnxt,
                                      beta, S + t * Q, S + (t + 1) * Q, neg_mw, N);
    __half* lt_ = lcur; lcur = lnxt; lnxt = lt_;
    float*  nt_ = ncur; ncur = nnxt; nnxt = nt_;
  }

  // psi_10 = softmax(ni_9 + h_9), entropy fused
  k_psi_ent<<<gridN, TPB, 0, stream>>>(ncur, beta, S + 9 * Q, neg_mw, out, H_acc, N);
  k_edge_stats<<<gridS, TPB, 0, stream>>>(out, src, dst, reg_acc, mod_acc, omw, m);
  k_finalize<<<1, 1, 0, stream>>>(H_acc, reg_acc, mod_acc, out + (size_t)N * Q,
                                  inv_m, inv_N, entc);
}

// Round 6
// 825.587 us; speedup vs baseline: 9.5090x; 1.1633x over previous
//
#include <hip/hip_runtime.h>
#include <hip/hip_fp16.h>
#include <math.h>

#define Q 8
#define TPB 256
#define WPB (TPB / 64)     // waves per block
#define SCAN_T 1024

struct alignas(16) H8 { __half h[8]; };

// ---------- helpers ----------

__device__ __forceinline__ float fast_rcp(float x) {
  return __builtin_amdgcn_rcpf(x);
}

__device__ __forceinline__ void load8(const float* __restrict__ p, float r[Q]) {
  const float4* p4 = reinterpret_cast<const float4*>(p);
  float4 a = p4[0], b = p4[1];
  r[0]=a.x; r[1]=a.y; r[2]=a.z; r[3]=a.w;
  r[4]=b.x; r[5]=b.y; r[6]=b.z; r[7]=b.w;
}

__device__ __forceinline__ void store8h(__half* __restrict__ p, const float r[Q]) {
  H8 t;
#pragma unroll
  for (int j=0;j<Q;j++) t.h[j] = __float2half(r[j]);
  *reinterpret_cast<H8*>(p) = t;
}

__device__ __forceinline__ float wave_sum(float x) {
  x += __shfl_down(x, 32);
  x += __shfl_down(x, 16);
  x += __shfl_down(x, 8);
  x += __shfl_down(x, 4);
  x += __shfl_down(x, 2);
  x += __shfl_down(x, 1);
  return x;
}

__device__ __forceinline__ void block_reduce_atomic(float x, float* target, float* lds) {
  float w = wave_sum(x);
  const int lane = threadIdx.x & 63, wid = threadIdx.x >> 6;
  if (lane == 0) lds[wid] = w;
  __syncthreads();
  if (threadIdx.x == 0) {
    float t = 0.f;
#pragma unroll
    for (int i = 0; i < WPB; i++) t += lds[i];
    atomicAdd(target, t);
  }
  __syncthreads();
}

// sum over the 8 lanes of an aligned 8-lane group (all lanes get result)
__device__ __forceinline__ float sum8_lanes(float x) {
  x += __shfl_xor(x, 1);
  x += __shfl_xor(x, 2);
  x += __shfl_xor(x, 4);
  return x;
}

// ---------- CSR build ----------

// count + local rank in one pass (pos[e] = rank of e within its dst bucket)
__global__ void k_count_pos(const int* __restrict__ dst, int* __restrict__ cnt,
                            int* __restrict__ pos, int E) {
  int e = blockIdx.x * TPB + threadIdx.x;
  if (e < E) pos[e] = atomicAdd(&cnt[dst[e]], 1);
}

__global__ void k_scan1(const int* __restrict__ cnt, int* __restrict__ row_ptr,
                        int* __restrict__ bsum, int N) {
  __shared__ int lds[SCAN_T];
  const int tid = threadIdx.x;
  const int i = blockIdx.x * SCAN_T + tid;
  int c = (i < N) ? cnt[i] : 0;
  lds[tid] = c;
  __syncthreads();
  for (int off = 1; off < SCAN_T; off <<= 1) {
    int v = (tid >= off) ? lds[tid - off] : 0;
    __syncthreads();
    lds[tid] += v;
    __syncthreads();
  }
  if (i < N) row_ptr[i] = lds[tid] - c;
  if (tid == SCAN_T - 1) bsum[blockIdx.x] = lds[tid];
}

__global__ void k_scan2(const int* __restrict__ bsum, int* __restrict__ boffs,
                        int* __restrict__ row_ptr, int nb, int N) {
  __shared__ int lds[SCAN_T];
  const int tid = threadIdx.x;
  int v = (tid < nb) ? bsum[tid] : 0;
  lds[tid] = v;
  __syncthreads();
  for (int off = 1; off < SCAN_T; off <<= 1) {
    int t = (tid >= off) ? lds[tid - off] : 0;
    __syncthreads();
    lds[tid] += t;
    __syncthreads();
  }
  if (tid < nb) boffs[tid] = lds[tid] - v;
  if (tid == 0) row_ptr[N] = lds[nb - 1];
}

__global__ void k_scan3(int* __restrict__ row_ptr, const int* __restrict__ boffs, int N) {
  int i = blockIdx.x * SCAN_T + threadIdx.x;
  if (i < N) row_ptr[i] += boffs[blockIdx.x];
}

// per edge pair: fixup pos -> global CSR position inline; write rn = {rev CSR pos,
// neighbor id}; scatter initial T = 1 + ew*normalized(msg) into CSR order.
__global__ void k_rn_init(const int* __restrict__ src, const int* __restrict__ dst,
                          const int* __restrict__ pos,
                          const int* __restrict__ row_ptr,
                          const float* __restrict__ msg_init,
                          const float* __restrict__ beta,
                          int2* __restrict__ rn, __half* __restrict__ tA,
                          int E, int m) {
  int i = blockIdx.x * TPB + threadIdx.x;
  if (i >= m) return;
  const float b  = beta[0];
  const float ew = expf(b) - 1.0f;
  const int u = src[i], v = dst[i];
  const int pu = pos[i] + row_ptr[v];       // edge i   (u -> v): in v's segment
  const int pv = pos[i + m] + row_ptr[u];   // edge i+m (v -> u): in u's segment
  int2 a; a.x = pv; a.y = u;
  int2 c; c.x = pu; c.y = v;
  rn[pu] = a;
  rn[pv] = c;

  float r0[Q], r1[Q];
  load8(msg_init + (size_t)i * Q, r0);
  load8(msg_init + ((size_t)i + (size_t)m) * Q, r1);
  float s0 = 0.f, s1 = 0.f;
#pragma unroll
  for (int j=0;j<Q;j++) { s0 += r0[j]; s1 += r1[j]; }
  float i0 = ew / s0, i1 = ew / s1;
#pragma unroll
  for (int j=0;j<Q;j++) { r0[j] = fmaf(r0[j], i0, 1.0f); r1[j] = fmaf(r1[j], i1, 1.0f); }
  store8h(tA + (size_t)pu * Q, r0);
  store8h(tA + (size_t)pv * Q, r1);
}

// ---------- init ----------

// pi0[u][j] = product over u's CSR segment of tA  ( = exp(node_in0) )
__global__ void k_pi0(const int* __restrict__ row_ptr, const __half* __restrict__ tA,
                      float* __restrict__ pi0, int N) {
  const int lane = threadIdx.x & 63;
  const int wid  = threadIdx.x >> 6;
  const int slot = lane >> 3;
  const int j    = lane & 7;
  const int wg = blockIdx.x * WPB + wid;
  const int ws = gridDim.x * WPB;
  for (int u = wg; u < N; u += ws) {
    const int s = row_ptr[u], e = row_ptr[u + 1];
    float prod = 1.f;
    for (int r = s + slot; r < e; r += 8) prod *= __half2float(tA[(size_t)r * Q + j]);
    prod *= __shfl_xor(prod, 8);
    prod *= __shfl_xor(prod, 16);
    prod *= __shfl_xor(prod, 32);
    if (slot == 0) pi0[(size_t)u * Q + j] = prod;
  }
}

__global__ void k_init_nodes(const float* __restrict__ psi_init,
                             float* __restrict__ S0, int N) {
  __shared__ float lds[WPB];
  int n = blockIdx.x * TPB + threadIdx.x;
  float p[Q];
  if (n < N) {
    load8(psi_init + (size_t)n * Q, p);
    float s = 0.f;
#pragma unroll
    for (int j=0;j<Q;j++) s += p[j];
    float inv = 1.0f / s;
#pragma unroll
    for (int j=0;j<Q;j++) p[j] *= inv;
  } else {
#pragma unroll
    for (int j=0;j<Q;j++) p[j] = 0.f;
  }
#pragma unroll
  for (int j=0;j<Q;j++) {
    block_reduce_atomic(p[j], &S0[j], lds);
  }
}

// ---------- per-iteration kernel (t-domain, no transcendentals) ----------
// Row r = edge (v -> u) in u's segment:
//   num[j]   = pi_t[v][j] * eh[j] / T_t[rev]          (scattered reads)
//   msg[j]   = num[j] / sum_j num                     (8-lane normalize)
//   T_{t+1}[r][j] = 1 + ew*msg[j]                     (contiguous fp16 write)
//   pi_{t+1}[u][j] = prod over segment of T_{t+1}     (register product)
//   psi_{t+1}[u] = normalize(pi_t[u]*eh) -> S_{t+1}   (block-reduced)
__global__ void k_iter(const int* __restrict__ row_ptr,
                       const int2* __restrict__ rn,
                       const __half* __restrict__ tIn,
                       __half* __restrict__ tOut,
                       const float* __restrict__ pi_cur,
                       float* __restrict__ pi_nxt,
                       const float* __restrict__ beta,
                       const float* __restrict__ S,
                       float* __restrict__ S_nxt,
                       float neg_mw, int N) {
  __shared__ float part[WPB][Q];
  const int lane = threadIdx.x & 63;
  const int wid  = threadIdx.x >> 6;
  const int slot = lane >> 3;
  const int j    = lane & 7;
  const float b  = beta[0];
  const float ew = expf(b) - 1.0f;
  const float eh = expf(neg_mw * b * S[j]);   // e^{h_j}
  float sacc = 0.f;

  const int wg = blockIdx.x * WPB + wid;
  const int ws = gridDim.x * WPB;
  for (int u = wg; u < N; u += ws) {
    const int s = row_ptr[u], e = row_ptr[u + 1];
    float prod = 1.f;
    int r = s + slot;
    int2 w; float vin = 1.f, piv = 0.f;
    if (r < e) {
      w   = rn[r];
      vin = __half2float(tIn[(size_t)w.x * Q + j]);   // scattered 16B/group read
      piv = pi_cur[(size_t)w.y * Q + j];              // L2-resident read
    }
    while (r < e) {
      const int r2 = r + 8;
      int2 w2; float vin2 = 1.f, piv2 = 0.f;
      if (r2 < e) {                                    // 2-deep pipeline: issue next
        w2   = rn[r2];                                 // loads before current reduce
        vin2 = __half2float(tIn[(size_t)w2.x * Q + j]);
        piv2 = pi_cur[(size_t)w2.y * Q + j];
      }
      const float num = piv * eh * fast_rcp(vin);
      const float sm  = sum8_lanes(num);
      const float pm  = num * fast_rcp(sm);            // new msg on edge (v->u)
      const float tn  = fmaf(pm, ew, 1.0f);            // T_{t+1}
      tOut[(size_t)r * Q + j] = __float2half(tn);      // contiguous write
      prod *= tn;
      r = r2; w = w2; vin = vin2; piv = piv2;
    }
    // pi_{t+1}[u] = product across slots
    prod *= __shfl_xor(prod, 8);
    prod *= __shfl_xor(prod, 16);
    prod *= __shfl_xor(prod, 32);
    if (slot == 0) {
      pi_nxt[(size_t)u * Q + j] = prod;
      // psi_{t+1}[u][j] for S_{t+1}
      const float pn = pi_cur[(size_t)u * Q + j] * eh;
      sacc += pn * fast_rcp(sum8_lanes(pn));
    }
  }
  if (slot == 0) part[wid][j] = sacc;
  __syncthreads();
  if (threadIdx.x < Q) {
    float tot = 0.f;
#pragma unroll
    for (int w = 0; w < WPB; w++) tot += part[w][threadIdx.x];
    atomicAdd(&S_nxt[threadIdx.x], tot);
  }
}

// ---------- finalization ----------

// psi = normalize(pi9 * e^{h9}) -> out; fused entropy. 8 lanes per node.
__global__ void k_psi_ent(const float* __restrict__ pi,
                          const float* __restrict__ beta,
                          const float* __restrict__ S,
                          float neg_mw, float* __restrict__ psi,
                          float* __restrict__ H_acc, int N) {
  __shared__ float lds[WPB];
  const int j = threadIdx.x & 7;
  const float eh = expf(neg_mw * beta[0] * S[j]);
  float hacc = 0.f;
  const int g0 = (blockIdx.x * TPB + threadIdx.x) >> 3;
  const int gs = (gridDim.x * TPB) >> 3;
  for (int n = g0; n < N; n += gs) {
    float pn = pi[(size_t)n * Q + j] * eh;
    float p = pn / sum8_lanes(pn);
    psi[(size_t)n * Q + j] = p;
    float el = p * logf(p + 1e-12f);
    el = sum8_lanes(el);
    if (j == 0) hacc += el;
  }
  block_reduce_atomic(hacc, H_acc, lds);
}

__global__ void k_edge_stats(const float* __restrict__ psi,
                             const int* __restrict__ src,
                             const int* __restrict__ dst,
                             float* __restrict__ reg_acc,
                             float* __restrict__ mod_acc,
                             float one_minus_mw, int m) {
  __shared__ float lds1[WPB];
  __shared__ float lds2[WPB];
  float reg = 0.f, mod = 0.f;
  for (int i = blockIdx.x * TPB + threadIdx.x; i < m; i += gridDim.x * TPB) {
    int u = src[i], v = dst[i];
    float pu[Q], pv[Q];
    load8(psi + (size_t)u * Q, pu);
    load8(psi + (size_t)v * Q, pv);
#pragma unroll
    for (int j=0;j<Q;j++) { float d = pu[j] - pv[j]; reg += d * d; }
    int au = 0, av = 0;
    float mu = pu[0], mv = pv[0];
#pragma unroll
    for (int j=1;j<Q;j++) {
      if (pu[j] > mu) { mu = pu[j]; au = j; }
      if (pv[j] > mv) { mv = pv[j]; av = j; }
    }
    if (au == av) mod += one_minus_mw;
  }
  block_reduce_atomic(reg, reg_acc, lds1);
  block_reduce_atomic(mod, mod_acc, lds2);
}

__global__ void k_finalize(const float* __restrict__ H_acc,
                           const float* __restrict__ reg_acc,
                           const float* __restrict__ mod_acc,
                           float* __restrict__ out3,
                           float inv_m, float inv_N, float entc) {
  out3[0] = reg_acc[0] * inv_m;
  out3[1] = (-H_acc[0] * inv_N) * entc;
  out3[2] = mod_acc[0] * inv_m;
}

// ---------- host ----------

extern "C" void kernel_launch(void* const* d_in, const int* in_sizes, int n_in,
                              void* d_out, int out_size, void* d_ws, size_t ws_size,
                              hipStream_t stream) {
  const float* msg_init = (const float*)d_in[0];
  const float* psi_init = (const float*)d_in[1];
  const float* beta     = (const float*)d_in[2];
  const int*   src      = (const int*)d_in[3];
  const int*   dst      = (const int*)d_in[4];

  const int E = in_sizes[3];
  const int m = E / 2;
  const int N = in_sizes[1] / Q;
  const double mean_w = (double)E / ((double)N * (double)N);
  const float  neg_mw = (float)(-mean_w);

  float* out = (float*)d_out;

  // ---- workspace layout ----
  __half* tA = (__half*)d_ws;                       // E*Q halves
  __half* tB = tA + (size_t)E * Q;                  // E*Q halves
  int2*  rn   = (int2*)(tB + (size_t)E * Q);        // E int2
  int*   pos  = (int*)(rn + E);                     // E
  int*   row_ptr = pos + E;                         // N+1
  int*   cnt     = row_ptr + (N + 1);               // N
  int*   bsum    = cnt + N;                         // SCAN_T
  int*   boffs   = bsum + SCAN_T;                   // SCAN_T
  float* pi0     = (float*)(boffs + SCAN_T);        // N*Q
  float* pi1     = pi0 + (size_t)N * Q;             // N*Q
  float* S       = pi1 + (size_t)N * Q;             // 11*Q
  float* H_acc   = S + 11 * Q;
  float* reg_acc = H_acc + 1;
  float* mod_acc = H_acc + 2;

  const int gridE = (E + TPB - 1) / TPB;
  const int gridM = (m + TPB - 1) / TPB;
  const int gridN = (N + TPB - 1) / TPB;
  const int gridI = min(2048, (N + WPB - 1) / WPB);
  const int gridS = min(512, gridM);
  const int nb    = (N + SCAN_T - 1) / SCAN_T;

  const float entc  = (float)(4.0 * log(0.5) / log(1.0 / (double)Q));
  const float inv_m = (float)(1.0 / (double)m);
  const float inv_N = (float)(1.0 / (double)N);
  const float omw   = (float)(1.0 - mean_w);

  hipMemsetAsync(cnt, 0, (size_t)N * sizeof(int), stream);
  hipMemsetAsync(S, 0, (size_t)(11 * Q + 3) * sizeof(float), stream);

  // CSR build
  k_count_pos<<<gridE, TPB, 0, stream>>>(dst, cnt, pos, E);
  k_scan1<<<nb, SCAN_T, 0, stream>>>(cnt, row_ptr, bsum, N);
  k_scan2<<<1, SCAN_T, 0, stream>>>(bsum, boffs, row_ptr, nb, N);
  k_scan3<<<nb, SCAN_T, 0, stream>>>(row_ptr, boffs, N);
  k_rn_init<<<gridM, TPB, 0, stream>>>(src, dst, pos, row_ptr, msg_init, beta,
                                       rn, tA, E, m);
  k_pi0<<<gridI, TPB, 0, stream>>>(row_ptr, tA, pi0, N);
  k_init_nodes<<<gridN, TPB, 0, stream>>>(psi_init, S, N);

  // 9 fused iterations in t-domain
  __half* tcur = tA; __half* tnxt = tB;
  float*  pcur = pi0; float* pnxt = pi1;
  for (int t = 0; t < 9; ++t) {
    k_iter<<<gridI, TPB, 0, stream>>>(row_ptr, rn, tcur, tnxt, pcur, pnxt,
                                      beta, S + t * Q, S + (t + 1) * Q, neg_mw, N);
    __half* th = tcur; tcur = tnxt; tnxt = th;
    float*  pf = pcur; pcur = pnxt; pnxt = pf;
  }

  // psi_10 = normalize(pi_9 * e^{h_9}), entropy fused
  k_psi_ent<<<gridN, TPB, 0, stream>>>(pcur, beta, S + 9 * Q, neg_mw, out, H_acc, N);
  k_edge_stats<<<gridS, TPB, 0, stream>>>(out, src, dst, reg_acc, mod_acc, omw, m);
  k_finalize<<<1, 1, 0, stream>>>(H_acc, reg_acc, mod_acc, out + (size_t)N * Q,
                                  inv_m, inv_N, entc);
}

// Round 7
// 740.615 us; speedup vs baseline: 10.5999x; 1.1147x over previous
//
#include <hip/hip_runtime.h>
#include <hip/hip_fp16.h>
#include <math.h>

#define Q 8
#define TPB 256
#define WPB (TPB / 64)     // waves per block
#define SCAN_T 1024

struct alignas(16) H8 { __half h[8]; };

// ---------- helpers ----------

__device__ __forceinline__ float fast_rcp(float x) {
  return __builtin_amdgcn_rcpf(x);
}

__device__ __forceinline__ void load8(const float* __restrict__ p, float r[Q]) {
  const float4* p4 = reinterpret_cast<const float4*>(p);
  float4 a = p4[0], b = p4[1];
  r[0]=a.x; r[1]=a.y; r[2]=a.z; r[3]=a.w;
  r[4]=b.x; r[5]=b.y; r[6]=b.z; r[7]=b.w;
}

__device__ __forceinline__ void store8h(__half* __restrict__ p, const float r[Q]) {
  H8 t;
#pragma unroll
  for (int j=0;j<Q;j++) t.h[j] = __float2half(r[j]);
  *reinterpret_cast<H8*>(p) = t;
}

__device__ __forceinline__ float wave_sum(float x) {
  x += __shfl_down(x, 32);
  x += __shfl_down(x, 16);
  x += __shfl_down(x, 8);
  x += __shfl_down(x, 4);
  x += __shfl_down(x, 2);
  x += __shfl_down(x, 1);
  return x;
}

__device__ __forceinline__ void block_reduce_atomic(float x, float* target, float* lds) {
  float w = wave_sum(x);
  const int lane = threadIdx.x & 63, wid = threadIdx.x >> 6;
  if (lane == 0) lds[wid] = w;
  __syncthreads();
  if (threadIdx.x == 0) {
    float t = 0.f;
#pragma unroll
    for (int i = 0; i < WPB; i++) t += lds[i];
    atomicAdd(target, t);
  }
  __syncthreads();
}

// sum over the 8 lanes of an aligned 8-lane group (all lanes get result)
__device__ __forceinline__ float sum8_lanes(float x) {
  x += __shfl_xor(x, 1);
  x += __shfl_xor(x, 2);
  x += __shfl_xor(x, 4);
  return x;
}

// ---------- CSR build ----------

// count + local rank; 4 edges per thread for atomic ILP
__global__ void k_count_pos(const int* __restrict__ dst, int* __restrict__ cnt,
                            int* __restrict__ pos, int E) {
  int i0 = (blockIdx.x * TPB + threadIdx.x) * 4;
  if (i0 + 3 < E) {
    int4 d = *reinterpret_cast<const int4*>(dst + i0);
    int p0 = atomicAdd(&cnt[d.x], 1);
    int p1 = atomicAdd(&cnt[d.y], 1);
    int p2 = atomicAdd(&cnt[d.z], 1);
    int p3 = atomicAdd(&cnt[d.w], 1);
    *reinterpret_cast<int4*>(pos + i0) = make_int4(p0, p1, p2, p3);
  } else {
    for (int e = i0; e < E; e++) pos[e] = atomicAdd(&cnt[dst[e]], 1);
  }
}

__global__ void k_scan1(const int* __restrict__ cnt, int* __restrict__ row_ptr,
                        int* __restrict__ bsum, int N) {
  __shared__ int lds[SCAN_T];
  const int tid = threadIdx.x;
  const int i = blockIdx.x * SCAN_T + tid;
  int c = (i < N) ? cnt[i] : 0;
  lds[tid] = c;
  __syncthreads();
  for (int off = 1; off < SCAN_T; off <<= 1) {
    int v = (tid >= off) ? lds[tid - off] : 0;
    __syncthreads();
    lds[tid] += v;
    __syncthreads();
  }
  if (i < N) row_ptr[i] = lds[tid] - c;
  if (tid == SCAN_T - 1) bsum[blockIdx.x] = lds[tid];
}

__global__ void k_scan2(const int* __restrict__ bsum, int* __restrict__ boffs,
                        int* __restrict__ row_ptr, int nb, int N) {
  __shared__ int lds[SCAN_T];
  const int tid = threadIdx.x;
  int v = (tid < nb) ? bsum[tid] : 0;
  lds[tid] = v;
  __syncthreads();
  for (int off = 1; off < SCAN_T; off <<= 1) {
    int t = (tid >= off) ? lds[tid - off] : 0;
    __syncthreads();
    lds[tid] += t;
    __syncthreads();
  }
  if (tid < nb) boffs[tid] = lds[tid] - v;
  if (tid == 0) row_ptr[N] = lds[nb - 1];
}

__global__ void k_scan3(int* __restrict__ row_ptr, const int* __restrict__ boffs, int N) {
  int i = blockIdx.x * SCAN_T + threadIdx.x;
  if (i < N) row_ptr[i] += boffs[blockIdx.x];
}

// per edge pair: rev-position links (4B scatters) + initial T = 1 + ew*norm(msg)
// scattered into CSR order (into the t0 scratch buffer).
__global__ void k_build(const int* __restrict__ src, const int* __restrict__ dst,
                        const int* __restrict__ pos, const int* __restrict__ row_ptr,
                        const float* __restrict__ msg_init,
                        const float* __restrict__ beta,
                        int* __restrict__ rev, __half* __restrict__ t0, int m) {
  int i = blockIdx.x * TPB + threadIdx.x;
  if (i >= m) return;
  const float b  = beta[0];
  const float ew = expf(b) - 1.0f;
  const int u = src[i], v = dst[i];
  const int pu = pos[i] + row_ptr[v];       // edge i   (u -> v): in v's segment
  const int pv = pos[i + m] + row_ptr[u];   // edge i+m (v -> u): in u's segment
  rev[pu] = pv;
  rev[pv] = pu;

  float r0[Q], r1[Q];
  load8(msg_init + (size_t)i * Q, r0);
  load8(msg_init + ((size_t)i + (size_t)m) * Q, r1);
  float s0 = 0.f, s1 = 0.f;
#pragma unroll
  for (int j=0;j<Q;j++) { s0 += r0[j]; s1 += r1[j]; }
  float i0 = ew / s0, i1 = ew / s1;
#pragma unroll
  for (int j=0;j<Q;j++) { r0[j] = fmaf(r0[j], i0, 1.0f); r1[j] = fmaf(r1[j], i1, 1.0f); }
  store8h(t0 + (size_t)pu * Q, r0);
  store8h(t0 + (size_t)pv * Q, r1);
}

// ---------- init ----------

// 8-thread group per node: pi0[u] = prod of T0 over segment; cav0[r] = norm(pi0/T0[r]).
__global__ void k_pi0cav(const int* __restrict__ row_ptr, const __half* __restrict__ t0,
                         __half* __restrict__ cav0, float* __restrict__ pi0, int N) {
  const int tid = threadIdx.x;
  const int s = tid & 7;
  const int u = (blockIdx.x * TPB + tid) >> 3;
  if (u >= N) return;
  const int st = row_ptr[u], en = row_ptr[u + 1];
  float prod[Q];
#pragma unroll
  for (int j=0;j<Q;j++) prod[j] = 1.f;
  for (int r = st + s; r < en; r += 8) {
    H8 t = *reinterpret_cast<const H8*>(t0 + (size_t)r * Q);
#pragma unroll
    for (int j=0;j<Q;j++) prod[j] *= __half2float(t.h[j]);
  }
#pragma unroll
  for (int j=0;j<Q;j++) {
    prod[j] *= __shfl_xor(prod[j], 1);
    prod[j] *= __shfl_xor(prod[j], 2);
    prod[j] *= __shfl_xor(prod[j], 4);
  }
  if (s == 0) {
    float4* o = reinterpret_cast<float4*>(pi0 + (size_t)u * Q);
    o[0] = make_float4(prod[0], prod[1], prod[2], prod[3]);
    o[1] = make_float4(prod[4], prod[5], prod[6], prod[7]);
  }
  for (int r = st + s; r < en; r += 8) {
    H8 t = *reinterpret_cast<const H8*>(t0 + (size_t)r * Q);
    float c[Q]; float sm = 0.f;
#pragma unroll
    for (int j=0;j<Q;j++) { c[j] = prod[j] * fast_rcp(__half2float(t.h[j])); sm += c[j]; }
    float inv = fast_rcp(sm);
    H8 o;
#pragma unroll
    for (int j=0;j<Q;j++) o.h[j] = __float2half(c[j] * inv);
    *reinterpret_cast<H8*>(cav0 + (size_t)r * Q) = o;
  }
}

__global__ void k_init_nodes(const float* __restrict__ psi_init,
                             float* __restrict__ S0, int N) {
  __shared__ float lds[WPB];
  int n = blockIdx.x * TPB + threadIdx.x;
  float p[Q];
  if (n < N) {
    load8(psi_init + (size_t)n * Q, p);
    float s = 0.f;
#pragma unroll
    for (int j=0;j<Q;j++) s += p[j];
    float inv = 1.0f / s;
#pragma unroll
    for (int j=0;j<Q;j++) p[j] *= inv;
  } else {
#pragma unroll
    for (int j=0;j<Q;j++) p[j] = 0.f;
  }
#pragma unroll
  for (int j=0;j<Q;j++) {
    block_reduce_atomic(p[j], &S0[j], lds);
  }
}

// ---------- per-iteration kernel (cavity form) ----------
// 8-thread group per node u; thread = row-slot, holds a full 8-component row.
// Row r in seg(u) (edge v->u):
//   c8   = cavIn[rev[r]]                 (ONE scattered 16B read)
//   msg  = normalize_j(eh * c8)
//   T[j] = 1 + ew*msg[j]  -> scratch write to cavOut[r]; prod *= T
// pi_{t+1}[u] = cross-thread product;  psi_{t+1}(u) -> S_nxt  (uses pi_t)
// second pass: cavOut[r] = normalize_j(pi_{t+1}/T[r])          (contiguous)
__global__ void k_iter2(const int* __restrict__ row_ptr,
                        const int* __restrict__ rev,
                        const __half* __restrict__ cavIn,
                        __half* __restrict__ cavOut,
                        const float* __restrict__ pi_cur,
                        float* __restrict__ pi_nxt,
                        const float* __restrict__ beta,
                        const float* __restrict__ S,
                        float* __restrict__ S_nxt,
                        float neg_mw, int N, int writeCav) {
  __shared__ float part[WPB][Q];
  const int tid = threadIdx.x;
  const int s = tid & 7;
  const float b  = beta[0];
  const float ew = expf(b) - 1.0f;
  const float hb = neg_mw * b;
  float eh[Q];
#pragma unroll
  for (int j=0;j<Q;j++) eh[j] = expf(hb * S[j]);
  const float ehs = expf(hb * S[s]);     // runtime-s copy (avoid reg-array dyn index)
  float sacc = 0.f;

  const int u = (blockIdx.x * TPB + tid) >> 3;
  if (u < N) {
    const int st = row_ptr[u], en = row_ptr[u + 1];
    float prod[Q];
#pragma unroll
    for (int j=0;j<Q;j++) prod[j] = 1.f;
    for (int r = st + s; r < en; r += 8) {
      const int rv = rev[r];
      H8 c = *reinterpret_cast<const H8*>(cavIn + (size_t)rv * Q);
      float num[Q]; float sm = 0.f;
#pragma unroll
      for (int j=0;j<Q;j++) { num[j] = eh[j] * __half2float(c.h[j]); sm += num[j]; }
      const float inv = fast_rcp(sm) * ew;
      H8 o;
#pragma unroll
      for (int j=0;j<Q;j++) {
        float tn = fmaf(num[j], inv, 1.0f);
        prod[j] *= tn;
        o.h[j] = __float2half(tn);
      }
      *reinterpret_cast<H8*>(cavOut + (size_t)r * Q) = o;   // scratch T, contiguous
    }
    // pi_{t+1}[u]: elementwise product across the 8 slot threads
#pragma unroll
    for (int j=0;j<Q;j++) {
      prod[j] *= __shfl_xor(prod[j], 1);
      prod[j] *= __shfl_xor(prod[j], 2);
      prod[j] *= __shfl_xor(prod[j], 4);
    }
    if (s == 0) {
      float4* o = reinterpret_cast<float4*>(pi_nxt + (size_t)u * Q);
      o[0] = make_float4(prod[0], prod[1], prod[2], prod[3]);
      o[1] = make_float4(prod[4], prod[5], prod[6], prod[7]);
    }
    // psi_{t+1}[u][s] contribution (distributed: thread s owns component s)
    {
      float pn = pi_cur[(size_t)u * Q + s] * ehs;
      float smp = sum8_lanes(pn);
      sacc = pn * fast_rcp(smp);
    }
    if (writeCav) {
      for (int r = st + s; r < en; r += 8) {
        H8 t = *reinterpret_cast<const H8*>(cavOut + (size_t)r * Q);  // L1-hot
        float c[Q]; float sm = 0.f;
#pragma unroll
        for (int j=0;j<Q;j++) { c[j] = prod[j] * fast_rcp(__half2float(t.h[j])); sm += c[j]; }
        const float inv = fast_rcp(sm);
        H8 o;
#pragma unroll
        for (int j=0;j<Q;j++) o.h[j] = __float2half(c[j] * inv);
        *reinterpret_cast<H8*>(cavOut + (size_t)r * Q) = o;
      }
    }
  }
  // S_nxt reduction: lanes with equal (tid&7) sum across the wave
  sacc += __shfl_xor(sacc, 8);
  sacc += __shfl_xor(sacc, 16);
  sacc += __shfl_xor(sacc, 32);
  const int lane = tid & 63, wid = tid >> 6;
  if (lane < Q) part[wid][lane] = sacc;
  __syncthreads();
  if (tid < Q) {
    float tot = 0.f;
#pragma unroll
    for (int w = 0; w < WPB; w++) tot += part[w][tid];
    atomicAdd(&S_nxt[tid], tot);
  }
}

// ---------- finalization ----------

__global__ void k_psi_ent(const float* __restrict__ pi,
                          const float* __restrict__ beta,
                          const float* __restrict__ S,
                          float neg_mw, float* __restrict__ psi,
                          float* __restrict__ H_acc, int N) {
  __shared__ float lds[WPB];
  const int j = threadIdx.x & 7;
  const float eh = expf(neg_mw * beta[0] * S[j]);
  float hacc = 0.f;
  const int g0 = (blockIdx.x * TPB + threadIdx.x) >> 3;
  const int gs = (gridDim.x * TPB) >> 3;
  for (int n = g0; n < N; n += gs) {
    float pn = pi[(size_t)n * Q + j] * eh;
    float p = pn / sum8_lanes(pn);
    psi[(size_t)n * Q + j] = p;
    float el = p * logf(p + 1e-12f);
    el = sum8_lanes(el);
    if (j == 0) hacc += el;
  }
  block_reduce_atomic(hacc, H_acc, lds);
}

__global__ void k_edge_stats(const float* __restrict__ psi,
                             const int* __restrict__ src,
                             const int* __restrict__ dst,
                             float* __restrict__ reg_acc,
                             float* __restrict__ mod_acc,
                             float one_minus_mw, int m) {
  __shared__ float lds1[WPB];
  __shared__ float lds2[WPB];
  float reg = 0.f, mod = 0.f;
  for (int i = blockIdx.x * TPB + threadIdx.x; i < m; i += gridDim.x * TPB) {
    int u = src[i], v = dst[i];
    float pu[Q], pv[Q];
    load8(psi + (size_t)u * Q, pu);
    load8(psi + (size_t)v * Q, pv);
#pragma unroll
    for (int j=0;j<Q;j++) { float d = pu[j] - pv[j]; reg += d * d; }
    int au = 0, av = 0;
    float mu = pu[0], mv = pv[0];
#pragma unroll
    for (int j=1;j<Q;j++) {
      if (pu[j] > mu) { mu = pu[j]; au = j; }
      if (pv[j] > mv) { mv = pv[j]; av = j; }
    }
    if (au == av) mod += one_minus_mw;
  }
  block_reduce_atomic(reg, reg_acc, lds1);
  block_reduce_atomic(mod, mod_acc, lds2);
}

__global__ void k_finalize(const float* __restrict__ H_acc,
                           const float* __restrict__ reg_acc,
                           const float* __restrict__ mod_acc,
                           float* __restrict__ out3,
                           float inv_m, float inv_N, float entc) {
  out3[0] = reg_acc[0] * inv_m;
  out3[1] = (-H_acc[0] * inv_N) * entc;
  out3[2] = mod_acc[0] * inv_m;
}

// ---------- host ----------

extern "C" void kernel_launch(void* const* d_in, const int* in_sizes, int n_in,
                              void* d_out, int out_size, void* d_ws, size_t ws_size,
                              hipStream_t stream) {
  const float* msg_init = (const float*)d_in[0];
  const float* psi_init = (const float*)d_in[1];
  const float* beta     = (const float*)d_in[2];
  const int*   src      = (const int*)d_in[3];
  const int*   dst      = (const int*)d_in[4];

  const int E = in_sizes[3];
  const int m = E / 2;
  const int N = in_sizes[1] / Q;
  const double mean_w = (double)E / ((double)N * (double)N);
  const float  neg_mw = (float)(-mean_w);

  float* out = (float*)d_out;

  // ---- workspace layout ----
  __half* cavA = (__half*)d_ws;                     // E*Q halves
  __half* cavB = cavA + (size_t)E * Q;              // E*Q halves (t0 scratch first)
  int*   rev     = (int*)(cavB + (size_t)E * Q);    // E
  int*   pos     = rev + E;                         // E
  int*   row_ptr = pos + E;                         // N+1
  int*   cnt     = row_ptr + (N + 1);               // N
  int*   bsum    = cnt + N;                         // SCAN_T
  int*   boffs   = bsum + SCAN_T;                   // SCAN_T
  float* pi0     = (float*)(boffs + SCAN_T);        // N*Q
  float* pi1     = pi0 + (size_t)N * Q;             // N*Q
  float* S       = pi1 + (size_t)N * Q;             // 11*Q
  float* H_acc   = S + 11 * Q;
  float* reg_acc = H_acc + 1;
  float* mod_acc = H_acc + 2;

  const int gridC = (E + TPB * 4 - 1) / (TPB * 4);
  const int gridM = (m + TPB - 1) / TPB;
  const int gridN = (N + TPB - 1) / TPB;
  const int gridG = (N * Q + TPB - 1) / TPB;        // 8-thread group per node
  const int gridS = min(512, gridM);
  const int nb    = (N + SCAN_T - 1) / SCAN_T;

  const float entc  = (float)(4.0 * log(0.5) / log(1.0 / (double)Q));
  const float inv_m = (float)(1.0 / (double)m);
  const float inv_N = (float)(1.0 / (double)N);
  const float omw   = (float)(1.0 - mean_w);

  hipMemsetAsync(cnt, 0, (size_t)N * sizeof(int), stream);
  hipMemsetAsync(S, 0, (size_t)(11 * Q + 3) * sizeof(float), stream);

  // CSR build
  k_count_pos<<<gridC, TPB, 0, stream>>>(dst, cnt, pos, E);
  k_scan1<<<nb, SCAN_T, 0, stream>>>(cnt, row_ptr, bsum, N);
  k_scan2<<<1, SCAN_T, 0, stream>>>(bsum, boffs, row_ptr, nb, N);
  k_scan3<<<nb, SCAN_T, 0, stream>>>(row_ptr, boffs, N);
  k_build<<<gridM, TPB, 0, stream>>>(src, dst, pos, row_ptr, msg_init, beta,
                                     rev, cavB, m);
  k_pi0cav<<<gridG, TPB, 0, stream>>>(row_ptr, cavB, cavA, pi0, N);
  k_init_nodes<<<gridN, TPB, 0, stream>>>(psi_init, S, N);

  // 9 fused cavity iterations
  __half* ccur = cavA; __half* cnxt = cavB;
  float*  pcur = pi0;  float*  pnxt = pi1;
  for (int t = 0; t < 9; ++t) {
    k_iter2<<<gridG, TPB, 0, stream>>>(row_ptr, rev, ccur, cnxt, pcur, pnxt,
                                       beta, S + t * Q, S + (t + 1) * Q,
                                       neg_mw, N, (t < 8) ? 1 : 0);
    __half* ch = ccur; ccur = cnxt; cnxt = ch;
    float*  pf = pcur; pcur = pnxt; pnxt = pf;
  }

  // psi_10 = normalize(pi_9 * e^{h_9}), entropy fused
  k_psi_ent<<<gridN, TPB, 0, stream>>>(pcur, beta, S + 9 * Q, neg_mw, out, H_acc, N);
  k_edge_stats<<<gridS, TPB, 0, stream>>>(out, src, dst, reg_acc, mod_acc, omw, m);
  k_finalize<<<1, 1, 0, stream>>>(H_acc, reg_acc, mod_acc, out + (size_t)N * Q,
                                  inv_m, inv_N, entc);
}